// Round 2
// baseline (212.396 us; speedup 1.0000x reference)
//
#include <hip/hip_runtime.h>
#include <hip/hip_bf16.h>

typedef __hip_bfloat16 bf16;

constexpr int T = 64, S = 32, F = 256, A = 64;
constexpr int R = T * S;  // 2048

// workspace layout (fp32 elements)
constexpr size_t OFF_XPH  = 0;                          // R*A
constexpr size_t OFF_TH   = OFF_XPH + (size_t)R * A;    // R*A
constexpr size_t OFF_UU   = OFF_TH  + (size_t)R * A;    // R*A
constexpr size_t OFF_DD   = OFF_UU  + (size_t)R * A;    // R*16
constexpr size_t OFF_POS  = OFF_DD  + (size_t)R * 16;   // S*S*64
constexpr size_t OFF_FLAG = OFF_POS + (size_t)S * S * 64; // 1 int

// flag-selected load: inputs are either fp32 or bf16 (decided at runtime)
__device__ __forceinline__ float ldv(const void* p, size_t i, int f32) {
    if (f32) return ((const float*)p)[i];
    return __bfloat162float(((const bf16*)p)[i]);
}

// ---------------------------------------------------------------------------
// Kernel 0: dtype probe. Interpret first 1024 elements of batch_data as bf16.
// Real bf16 N(0,1) data => |v| <= ~5. fp32 data misread as bf16 => random
// exponents, |v| huge / NaN with overwhelming probability.
// ---------------------------------------------------------------------------
__global__ void k_detect(const unsigned short* __restrict__ bd_u16,
                         int* __restrict__ flag)
{
    int bad = 0;
    for (int i = threadIdx.x; i < 1024; i += 64) {
        unsigned int u = ((unsigned int)bd_u16[i]) << 16;
        float f = __uint_as_float(u);
        if (!(fabsf(f) <= 100.f)) bad = 1;   // catches NaN too
    }
    const int any_bad = __any(bad) ? 1 : 0;
    if (threadIdx.x == 0) *flag = any_bad;
}

// ---------------------------------------------------------------------------
// Kernel 1: per x-row precompute.
//   theta = x @ Wa + ba         (64)   -> th
//   x_phi = x @ Wb[:F]          (64)   -> xph
//   u     = WbP @ theta         (64)   -> uu   (WbP = Wb[F:])
//   d10   = Wtmp @ u            (10)   -> dd
// ---------------------------------------------------------------------------
__global__ __launch_bounds__(256) void k_pre(
    const void* __restrict__ bd, const void* __restrict__ Wa,
    const void* __restrict__ ba, const void* __restrict__ Wb,
    const void* __restrict__ Wtmp,
    float* __restrict__ xph, float* __restrict__ th,
    float* __restrict__ uu, float* __restrict__ dd,
    const int* __restrict__ flag)
{
    const int f32 = *flag;
    const int row = blockIdx.x;      // 0..2047
    const int tid = threadIdx.x;     // 0..255
    __shared__ float xs[256];
    __shared__ float ths[64];
    __shared__ float us[64];

    xs[tid] = ldv(bd, (size_t)row * 256 + tid, f32);
    __syncthreads();

    if (tid < 64) {
        float a2 = ldv(ba, tid, f32);
#pragma unroll 8
        for (int c = 0; c < 256; ++c) a2 += xs[c] * ldv(Wa, (size_t)c * 64 + tid, f32);
        th[row * 64 + tid] = a2;
        ths[tid] = a2;
    } else if (tid < 128) {
        const int a = tid - 64;
        float a2 = 0.f;
#pragma unroll 8
        for (int c = 0; c < 256; ++c) a2 += xs[c] * ldv(Wb, (size_t)c * 64 + a, f32);
        xph[row * 64 + a] = a2;
    }
    __syncthreads();

    if (tid < 64) {   // u[p] = sum_a WbP[p,a] * theta[a]
        float a2 = 0.f;
#pragma unroll 8
        for (int a = 0; a < 64; ++a) a2 += ths[a] * ldv(Wb, (size_t)(256 + tid) * 64 + a, f32);
        uu[row * 64 + tid] = a2;
        us[tid] = a2;
    }
    __syncthreads();

    if (tid < 10) {   // d10[q] = sum_p Wtmp[q,p] * u[p]
        float a2 = 0.f;
#pragma unroll
        for (int p = 0; p < 64; ++p) a2 += us[p] * ldv(Wtmp, (size_t)tid * 64 + p, f32);
        dd[row * 16 + tid] = a2;
    }
}

// ---------------------------------------------------------------------------
// Kernel 2: pos[j,k,p] (32*32*64) = concat(positions[e] @ Wpos + bpos)
// ---------------------------------------------------------------------------
__global__ __launch_bounds__(256) void k_pos(
    const void* __restrict__ positions, const void* __restrict__ Wpos,
    const void* __restrict__ bpos, float* __restrict__ pos,
    const int* __restrict__ flag)
{
    const int f32 = *flag;
    const int idx = blockIdx.x * 256 + threadIdx.x;  // (j*32+k)*64 + p
    const int p = idx & 63;
    const int jk = idx >> 6;
    const int e = p >> 5;
    const int pp = p & 31;
    const size_t src = (size_t)(e * 1024 + jk) * 9;
    float acc = ldv(bpos, pp, f32);
#pragma unroll
    for (int q = 0; q < 9; ++q) acc += ldv(positions, src + q, f32) * ldv(Wpos, (size_t)q * 32 + pp, f32);
    pos[idx] = acc;
}

// ---------------------------------------------------------------------------
// Kernel 3: fused dual attention for one (tt, ss) output row per block.
// Spatial (i=tt, j=ss): sc_s[k] = th.xph[tt,k] + u.pos[ss,k]
// Temporal (j=tt, i=ss): sc_t[t] = th.xph[t,ss] + d10.temp[tt,t,ss]
// xc = sm_s . x[tt,k,:] + sm_t . x[t,ss,:]        (256)
// out = xc@WgX + gsum@WgP + 2*bg, gsum = pv/Z_s + (w10@Wtmp)/Z_t + btmp
// ---------------------------------------------------------------------------
__global__ __launch_bounds__(256) void k_main(
    const void* __restrict__ bd, const void* __restrict__ temp,
    const void* __restrict__ Wg, const void* __restrict__ bg,
    const void* __restrict__ Wtmp, const void* __restrict__ btmp,
    const float* __restrict__ xph, const float* __restrict__ th,
    const float* __restrict__ uu, const float* __restrict__ dd,
    const float* __restrict__ pos, void* __restrict__ outp,
    const int* __restrict__ flag)
{
    const int f32 = *flag;
    const int blk = blockIdx.x;        // r = tt*32 + ss
    const int tt = blk >> 5;
    const int ss = blk & 31;
    const int tid = threadIdx.x;

    __shared__ float th_s[64], u_s[64], d_s[10];
    __shared__ float es[32], et[64];
    __shared__ float gsum[64], w10[10];
    __shared__ float xc[256];

    if (tid < 64) { th_s[tid] = th[blk * 64 + tid]; u_s[tid] = uu[blk * 64 + tid]; }
    if (tid < 10) d_s[tid] = dd[blk * 16 + tid];
    __syncthreads();

    // ---- scores ----
    if (tid < 32) {
        const int k = tid;
        const float* xp = xph + (tt * 32 + k) * 64;
        const float* pp = pos + (ss * 32 + k) * 64;
        float sc = 0.f;
#pragma unroll 8
        for (int a = 0; a < 64; ++a) sc += th_s[a] * xp[a];
#pragma unroll 8
        for (int p = 0; p < 64; ++p) sc += u_s[p] * pp[p];
        es[k] = sc;
    } else if (tid >= 64 && tid < 128) {
        const int t = tid - 64;
        const float* xp = xph + (t * 32 + ss) * 64;
        const size_t tp = ((size_t)(tt * 64 + t) * 32 + ss) * 10;
        float sc = 0.f;
#pragma unroll 8
        for (int a = 0; a < 64; ++a) sc += th_s[a] * xp[a];
#pragma unroll
        for (int q = 0; q < 10; ++q) sc += d_s[q] * ldv(temp, tp + q, f32);
        et[t] = sc;
    }
    __syncthreads();

    // ---- softmax (redundant scan per thread) ----
    float ms = -1e30f, mt = -1e30f;
#pragma unroll 8
    for (int k = 0; k < 32; ++k) ms = fmaxf(ms, es[k]);
#pragma unroll 8
    for (int t = 0; t < 64; ++t) mt = fmaxf(mt, et[t]);
    __syncthreads();   // all raw-score reads done
    if (tid < 32) es[tid] = __expf(es[tid] - ms);
    if (tid >= 64 && tid < 128) et[tid - 64] = __expf(et[tid - 64] - mt);
    __syncthreads();
    float sum_s = 0.f, sum_t = 0.f;
#pragma unroll 8
    for (int k = 0; k < 32; ++k) sum_s += es[k];
#pragma unroll 8
    for (int t = 0; t < 64; ++t) sum_t += et[t];
    const float inv_s = 1.f / sum_s, inv_t = 1.f / sum_t;

    // ---- attn-weighted x combination (all threads, one f each) ----
    {
        const int f = tid;
        float accs = 0.f, acct = 0.f;
#pragma unroll 4
        for (int k = 0; k < 32; ++k)
            accs += es[k] * ldv(bd, (size_t)(tt * 32 + k) * 256 + f, f32);
#pragma unroll 4
        for (int t = 0; t < 64; ++t)
            acct += et[t] * ldv(bd, (size_t)(t * 32 + ss) * 256 + f, f32);
        xc[f] = accs * inv_s + acct * inv_t;
    }

    // ---- attn-weighted low-rank terms ----
    float pv = 0.f;
    if (tid < 64) {      // pv[p] = sum_k es[k] * pos[ss,k,p]
#pragma unroll 8
        for (int k = 0; k < 32; ++k) pv += es[k] * pos[(ss * 32 + k) * 64 + tid];
    } else if (tid < 74) {  // w10[q] = sum_t et[t] * temp[tt,t,ss,q]
        const int q = tid - 64;
        float a2 = 0.f;
        for (int t = 0; t < 64; ++t)
            a2 += et[t] * ldv(temp, ((size_t)(tt * 64 + t) * 32 + ss) * 10 + q, f32);
        w10[q] = a2;
    }
    __syncthreads();
    if (tid < 64) {      // gsum[p] = pv/Z_s + (w10@Wtmp[:,p])/Z_t + btmp[p]
        float v = 0.f;
#pragma unroll
        for (int q = 0; q < 10; ++q) v += w10[q] * ldv(Wtmp, (size_t)q * 64 + tid, f32);
        gsum[tid] = pv * inv_s + v * inv_t + ldv(btmp, tid, f32);
    }
    __syncthreads();

    // ---- epilogue: out[f] = xc@WgX[:,f] + gsum@WgP[:,f] + 2*bg[f] ----
    const int f = tid;
    float accg = 0.f;
#pragma unroll 8
    for (int c = 0; c < 256; ++c) accg += xc[c] * ldv(Wg, (size_t)c * 256 + f, f32);
#pragma unroll 8
    for (int p = 0; p < 64; ++p) accg += gsum[p] * ldv(Wg, (size_t)(256 + p) * 256 + f, f32);
    const float res = accg + 2.f * ldv(bg, f, f32);
    if (f32) ((float*)outp)[(size_t)blk * 256 + f] = res;
    else     ((bf16*)outp)[(size_t)blk * 256 + f] = __float2bfloat16(res);
}

extern "C" void kernel_launch(void* const* d_in, const int* in_sizes, int n_in,
                              void* d_out, int out_size, void* d_ws, size_t ws_size,
                              hipStream_t stream) {
    const void* bd   = d_in[0];
    const void* positions = d_in[1];
    const void* temp = d_in[2];
    const void* Wa   = d_in[3];
    const void* ba   = d_in[4];
    const void* Wb   = d_in[5];
    // d_in[6] = bb  (constant shift inside both softmaxes; cancels)
    const void* Wg   = d_in[7];
    const void* bg   = d_in[8];
    const void* Wpos = d_in[9];
    const void* bpos = d_in[10];
    const void* Wtmp = d_in[11];
    const void* btmp = d_in[12];

    float* ws  = (float*)d_ws;
    float* xph = ws + OFF_XPH;
    float* th  = ws + OFF_TH;
    float* uu  = ws + OFF_UU;
    float* dd  = ws + OFF_DD;
    float* pos = ws + OFF_POS;
    int*   flag = (int*)(ws + OFF_FLAG);

    k_detect<<<1, 64, 0, stream>>>((const unsigned short*)bd, flag);
    k_pre<<<R, 256, 0, stream>>>(bd, Wa, ba, Wb, Wtmp, xph, th, uu, dd, flag);
    k_pos<<<(S * S * 64) / 256, 256, 0, stream>>>(positions, Wpos, bpos, pos, flag);
    k_main<<<R, 256, 0, stream>>>(bd, temp, Wg, bg, Wtmp, btmp,
                                  xph, th, uu, dd, pos, d_out, flag);
}

// Round 3
// 154.394 us; speedup vs baseline: 1.3757x; 1.3757x over previous
//
#include <hip/hip_runtime.h>
#include <hip/hip_bf16.h>

constexpr int T = 64, S = 32, F = 256, A = 64;
constexpr int R = T * S;  // 2048

// workspace layout (fp32 elements)
constexpr size_t OFF_XPH = 0;                           // R*A
constexpr size_t OFF_TH  = OFF_XPH + (size_t)R * A;     // R*A
constexpr size_t OFF_UU  = OFF_TH  + (size_t)R * A;     // R*A
constexpr size_t OFF_DD  = OFF_UU  + (size_t)R * A;     // R*16
constexpr size_t OFF_POS = OFF_DD  + (size_t)R * 16;    // S*S*64
constexpr size_t OFF_Z   = OFF_POS + (size_t)S * S * 64;// R*320

// ---------------------------------------------------------------------------
// K1: blocks 0..511: 4 x-rows each (all 256 threads active).
//   th  = x@Wa + ba (64), xph = x@WbX (64)  — fused over c, shared xs read
//   uu  = WbP @ th (64),  dd = Wtmp @ uu (10)
// blocks 512..767: pos[j,k,p] = concat(positions[e]@Wpos + bpos)
// ---------------------------------------------------------------------------
__global__ __launch_bounds__(256) void k_pre(
    const float* __restrict__ bd, const float* __restrict__ Wa,
    const float* __restrict__ ba, const float* __restrict__ Wb,
    const float* __restrict__ Wtmp, const float* __restrict__ positions,
    const float* __restrict__ Wpos, const float* __restrict__ bpos,
    float* __restrict__ xph, float* __restrict__ th,
    float* __restrict__ uu, float* __restrict__ dd, float* __restrict__ pos)
{
    const int blk = blockIdx.x;
    const int tid = threadIdx.x;

    if (blk >= 512) {  // ---- pos blocks ----
        const int idx = (blk - 512) * 256 + tid;   // (j*32+k)*64 + p
        const int p = idx & 63, jk = idx >> 6;
        const int e = p >> 5, pp = p & 31;
        const float* src = positions + (size_t)(e * 1024 + jk) * 9;
        float acc = bpos[pp];
#pragma unroll
        for (int q = 0; q < 9; ++q) acc += src[q] * Wpos[q * 32 + pp];
        pos[idx] = acc;
        return;
    }

    __shared__ float xs[4][256];
    __shared__ float ths[4][64];
    __shared__ float us[4][64];
    const int rl = tid >> 6, lane = tid & 63;
    const int row = blk * 4 + rl;

    *(float4*)&xs[rl][lane * 4] = *(const float4*)&bd[(size_t)row * 256 + lane * 4];
    __syncthreads();

    float accA = ba[lane], accB = 0.f;
#pragma unroll 8
    for (int c = 0; c < 256; ++c) {
        const float xv = xs[rl][c];              // LDS broadcast
        accA += xv * Wa[c * 64 + lane];          // coalesced per wave
        accB += xv * Wb[c * 64 + lane];
    }
    th[row * 64 + lane]  = accA;
    ths[rl][lane] = accA;
    xph[row * 64 + lane] = accB;
    __syncthreads();

    float accU = 0.f;
#pragma unroll 8
    for (int a = 0; a < 64; ++a) accU += ths[rl][a] * Wb[(256 + lane) * 64 + a];
    uu[row * 64 + lane] = accU;
    us[rl][lane] = accU;
    __syncthreads();

    if (lane < 10) {
        float accD = 0.f;
#pragma unroll
        for (int p2 = 0; p2 < 64; ++p2) accD += us[rl][p2] * Wtmp[lane * 64 + p2];
        dd[row * 16 + lane] = accD;
    }
}

// ---------------------------------------------------------------------------
// K2: one block per output row r=(tt,ss).
//   sc_s[k] = th.xph[tt,k] + u.pos[ss,k]   (32, lanes 0-31 of wave 0)
//   sc_t[t] = th.xph[t,ss] + dd.temp[tt,t,ss] (64, wave 1)
//   softmax via shuffle butterflies; store NORMALIZED weights to LDS.
//   Z[r,f]     = sum_k a_s[k] x[tt,k,f] + sum_t a_t[t] x[t,ss,f]
//   Z[r,256+p] = sum_k a_s pos[ss,k,p] + (sum_t a_t temp..)@Wtmp + btmp
// ---------------------------------------------------------------------------
__global__ __launch_bounds__(256) void k_attn(
    const float* __restrict__ bd, const float* __restrict__ temp,
    const float* __restrict__ Wtmp, const float* __restrict__ btmp,
    const float* __restrict__ xph, const float* __restrict__ th,
    const float* __restrict__ uu, const float* __restrict__ dd,
    const float* __restrict__ pos, float* __restrict__ Z)
{
    const int r = blockIdx.x;
    const int tt = r >> 5, ss = r & 31;
    const int tid = threadIdx.x;

    __shared__ float th_s[64], u_s[64], d_s[16];
    __shared__ float es[32], et[64], w10[10];

    if (tid < 64)       th_s[tid] = th[(size_t)r * 64 + tid];
    else if (tid < 128) u_s[tid - 64] = uu[(size_t)r * 64 + (tid - 64)];
    else if (tid < 138) d_s[tid - 128] = dd[(size_t)r * 16 + (tid - 128)];
    __syncthreads();

    if (tid < 32) {                 // ---- spatial scores ----
        const int k = tid;
        const float4* xp = (const float4*)(xph + (size_t)(tt * 32 + k) * 64);
        const float4* pp = (const float4*)(pos + (size_t)(ss * 32 + k) * 64);
        const float4* tv = (const float4*)th_s;
        const float4* uv = (const float4*)u_s;
        float sc = 0.f;
#pragma unroll
        for (int a = 0; a < 16; ++a) {
            const float4 x4 = xp[a], t4 = tv[a];
            sc += x4.x * t4.x + x4.y * t4.y + x4.z * t4.z + x4.w * t4.w;
            const float4 p4 = pp[a], u4 = uv[a];
            sc += p4.x * u4.x + p4.y * u4.y + p4.z * u4.z + p4.w * u4.w;
        }
        float m = sc;               // 32-lane butterfly (offsets stay in [0,32))
#pragma unroll
        for (int off = 16; off; off >>= 1) m = fmaxf(m, __shfl_xor(m, off));
        const float e = __expf(sc - m);
        float s = e;
#pragma unroll
        for (int off = 16; off; off >>= 1) s += __shfl_xor(s, off);
        es[k] = e / s;              // normalized
    } else if (tid >= 64 && tid < 128) {   // ---- temporal scores ----
        const int t = tid - 64;
        const float4* xp = (const float4*)(xph + (size_t)(t * 32 + ss) * 64);
        const float4* tv = (const float4*)th_s;
        float sc = 0.f;
#pragma unroll
        for (int a = 0; a < 16; ++a) {
            const float4 x4 = xp[a], t4 = tv[a];
            sc += x4.x * t4.x + x4.y * t4.y + x4.z * t4.z + x4.w * t4.w;
        }
        const float2* tp = (const float2*)(temp + ((size_t)(tt * 64 + t) * 32 + ss) * 10);
        const float2* dv = (const float2*)d_s;
#pragma unroll
        for (int q = 0; q < 5; ++q) {
            const float2 t2 = tp[q], d2 = dv[q];
            sc += t2.x * d2.x + t2.y * d2.y;
        }
        float m = sc;               // full 64-lane butterfly
#pragma unroll
        for (int off = 32; off; off >>= 1) m = fmaxf(m, __shfl_xor(m, off));
        const float e = __expf(sc - m);
        float s = e;
#pragma unroll
        for (int off = 32; off; off >>= 1) s += __shfl_xor(s, off);
        et[t] = e / s;              // normalized
    }
    __syncthreads();

    // ---- xc: all 256 threads, one f each, coalesced bd reads ----
    {
        const int f = tid;
        float acc = 0.f;
        const float* bs = bd + (size_t)tt * 32 * 256 + f;
#pragma unroll 4
        for (int k = 0; k < 32; ++k) acc += es[k] * bs[(size_t)k * 256];
        const float* bt = bd + (size_t)ss * 256 + f;
#pragma unroll 4
        for (int t = 0; t < 64; ++t) acc += et[t] * bt[(size_t)t * 32 * 256];
        Z[(size_t)r * 320 + f] = acc;
    }

    // ---- low-rank value terms ----
    float pv = 0.f;
    if (tid < 64) {                 // pv[p] = sum_k a_s[k] pos[ss,k,p]
        const float* pb = pos + (size_t)ss * 32 * 64 + tid;
#pragma unroll 4
        for (int k = 0; k < 32; ++k) pv += es[k] * pb[(size_t)k * 64];
    } else if (tid < 74) {          // w10[q] = sum_t a_t[t] temp[tt,t,ss,q]
        const int q = tid - 64;
        const float* tb = temp + ((size_t)tt * 64 * 32 + ss) * 10 + q;
        float a2 = 0.f;
        for (int t = 0; t < 64; ++t) a2 += et[t] * tb[(size_t)t * 320];
        w10[q] = a2;
    }
    __syncthreads();
    if (tid < 64) {
        float v = 0.f;
#pragma unroll
        for (int q = 0; q < 10; ++q) v += w10[q] * Wtmp[q * 64 + tid];
        Z[(size_t)r * 320 + 256 + tid] = pv + v + btmp[tid];
    }
}

// ---------------------------------------------------------------------------
// K3: out[r,f] = Z[r,:]@Wg[:,f] + 2*bg[f].  8 rows per block; Wg coalesced,
// reused across rows; Z reads are wave-uniform (scalar-load friendly).
// ---------------------------------------------------------------------------
__global__ __launch_bounds__(256) void k_out(
    const float* __restrict__ Z, const float* __restrict__ Wg,
    const float* __restrict__ bg, float* __restrict__ out)
{
    const int f = threadIdx.x;
    const int r0 = blockIdx.x * 8;
    const float* z0 = Z + (size_t)r0 * 320;
    float acc[8] = {0.f, 0.f, 0.f, 0.f, 0.f, 0.f, 0.f, 0.f};
#pragma unroll 4
    for (int k = 0; k < 320; ++k) {
        const float wv = Wg[(size_t)k * 256 + f];
#pragma unroll
        for (int j = 0; j < 8; ++j) acc[j] += z0[(size_t)j * 320 + k] * wv;
    }
    const float b2 = 2.f * bg[f];
#pragma unroll
    for (int j = 0; j < 8; ++j) out[(size_t)(r0 + j) * 256 + f] = acc[j] + b2;
}

extern "C" void kernel_launch(void* const* d_in, const int* in_sizes, int n_in,
                              void* d_out, int out_size, void* d_ws, size_t ws_size,
                              hipStream_t stream) {
    const float* bd   = (const float*)d_in[0];
    const float* positions = (const float*)d_in[1];
    const float* temp = (const float*)d_in[2];
    const float* Wa   = (const float*)d_in[3];
    const float* ba   = (const float*)d_in[4];
    const float* Wb   = (const float*)d_in[5];
    // d_in[6] = bb: constant shift inside both softmaxes; cancels
    const float* Wg   = (const float*)d_in[7];
    const float* bg   = (const float*)d_in[8];
    const float* Wpos = (const float*)d_in[9];
    const float* bpos = (const float*)d_in[10];
    const float* Wtmp = (const float*)d_in[11];
    const float* btmp = (const float*)d_in[12];
    float* out = (float*)d_out;

    float* ws  = (float*)d_ws;
    float* xph = ws + OFF_XPH;
    float* th  = ws + OFF_TH;
    float* uu  = ws + OFF_UU;
    float* dd  = ws + OFF_DD;
    float* pos = ws + OFF_POS;
    float* Z   = ws + OFF_Z;

    k_pre<<<768, 256, 0, stream>>>(bd, Wa, ba, Wb, Wtmp, positions, Wpos, bpos,
                                   xph, th, uu, dd, pos);
    k_attn<<<R, 256, 0, stream>>>(bd, temp, Wtmp, btmp, xph, th, uu, dd, pos, Z);
    k_out<<<R / 8, 256, 0, stream>>>(Z, Wg, bg, out);
}

// Round 4
// 148.851 us; speedup vs baseline: 1.4269x; 1.0372x over previous
//
#include <hip/hip_runtime.h>

constexpr int T = 64, S = 32, F = 256, A = 64;
constexpr int R = T * S;  // 2048

// workspace layout (fp32 elements)
constexpr size_t OFF_XPH = 0;                           // R*A
constexpr size_t OFF_TH  = OFF_XPH + (size_t)R * A;     // R*A
constexpr size_t OFF_UU  = OFF_TH  + (size_t)R * A;     // R*A
constexpr size_t OFF_DD  = OFF_UU  + (size_t)R * A;     // R*16
constexpr size_t OFF_POS = OFF_DD  + (size_t)R * 16;    // S*S*64
constexpr size_t OFF_Z   = OFF_POS + (size_t)S * S * 64;// R*320

__device__ __forceinline__ float dot4(float4 a, float4 b) {
    return a.x * b.x + a.y * b.y + a.z * b.z + a.w * b.w;
}

// ---------------------------------------------------------------------------
// K1: blocks 0..255: 8 x-rows each (2 rows per wave).
//   th = x@Wa + ba, xph = x@WbX   (fused c-loop: 1 Wa + 1 Wb load -> 4 FMA)
//   uu = WbP@th, dd = Wtmp@uu
// blocks 256..511: pos[j,k,p] = concat(positions[e]@Wpos + bpos)
// ---------------------------------------------------------------------------
__global__ __launch_bounds__(256) void k_pre(
    const float* __restrict__ bd, const float* __restrict__ Wa,
    const float* __restrict__ ba, const float* __restrict__ Wb,
    const float* __restrict__ Wtmp, const float* __restrict__ positions,
    const float* __restrict__ Wpos, const float* __restrict__ bpos,
    float* __restrict__ xph, float* __restrict__ th,
    float* __restrict__ uu, float* __restrict__ dd, float* __restrict__ pos)
{
    const int blk = blockIdx.x;
    const int tid = threadIdx.x;

    if (blk >= 256) {  // ---- pos blocks ----
        const int idx = (blk - 256) * 256 + tid;   // (j*32+k)*64 + p
        const int p = idx & 63, jk = idx >> 6;
        const int e = p >> 5, pp = p & 31;
        const float* src = positions + (size_t)(e * 1024 + jk) * 9;
        float acc = bpos[pp];
#pragma unroll
        for (int q = 0; q < 9; ++q) acc += src[q] * Wpos[q * 32 + pp];
        pos[idx] = acc;
        return;
    }

    __shared__ float xs[8 * 256];
    __shared__ float ths[8][64];
    __shared__ float us[8][64];
    const int w = tid >> 6, lane = tid & 63;
    const int row0 = blk * 8 + 2 * w;          // this wave's two rows

    {   // stage 8 rows of x: 512 float4s over 256 threads
        const float4* src = (const float4*)(bd + (size_t)blk * 8 * 256);
        float4* dst = (float4*)xs;
        dst[tid] = src[tid];
        dst[tid + 256] = src[tid + 256];
    }
    __syncthreads();

    const float* x0 = xs + (2 * w) * 256;
    const float* x1 = xs + (2 * w + 1) * 256;
    float accA0 = ba[lane], accA1 = accA0, accB0 = 0.f, accB1 = 0.f;
#pragma unroll 8
    for (int c = 0; c < 256; ++c) {
        const float wa = Wa[c * 64 + lane];
        const float wb = Wb[c * 64 + lane];
        const float xa = x0[c], xb = x1[c];
        accA0 += xa * wa; accA1 += xb * wa;
        accB0 += xa * wb; accB1 += xb * wb;
    }
    th[(size_t)row0 * 64 + lane] = accA0;
    th[(size_t)(row0 + 1) * 64 + lane] = accA1;
    xph[(size_t)row0 * 64 + lane] = accB0;
    xph[(size_t)(row0 + 1) * 64 + lane] = accB1;
    ths[2 * w][lane] = accA0; ths[2 * w + 1][lane] = accA1;
    __syncthreads();

    float accU0 = 0.f, accU1 = 0.f;
#pragma unroll 8
    for (int a = 0; a < 64; ++a) {
        const float wp = Wb[(256 + lane) * 64 + a];
        accU0 += ths[2 * w][a] * wp;
        accU1 += ths[2 * w + 1][a] * wp;
    }
    uu[(size_t)row0 * 64 + lane] = accU0;
    uu[(size_t)(row0 + 1) * 64 + lane] = accU1;
    us[2 * w][lane] = accU0; us[2 * w + 1][lane] = accU1;
    __syncthreads();

    const int rsel = lane >> 4, q = lane & 15;
    if (rsel < 2 && q < 10) {
        float accD = 0.f;
#pragma unroll 8
        for (int p2 = 0; p2 < 64; ++p2) accD += us[2 * w + rsel][p2] * Wtmp[q * 64 + p2];
        dd[(size_t)(row0 + rsel) * 16 + q] = accD;
    }
}

// ---------------------------------------------------------------------------
// K2: one block per (ss, 4 consecutive tt).  blockIdx = ss*16 + tt0/4.
// Phase A: all 4 waves do temporal scores (wave w = row tt0+w, lane = t);
//          softmax + w10 fused via shuffle butterflies (temp read ONCE).
//          waves 0-1 then do 4x32 spatial scores.
// Phase B: xc for 4 rows, temporal bd loads shared across rows.
// Phase C: pv + gsum per wave.  2 barriers total.
// ---------------------------------------------------------------------------
__global__ __launch_bounds__(256) void k_attn(
    const float* __restrict__ bd, const float* __restrict__ temp,
    const float* __restrict__ Wtmp, const float* __restrict__ btmp,
    const float* __restrict__ xph, const float* __restrict__ th,
    const float* __restrict__ uu, const float* __restrict__ dd,
    const float* __restrict__ pos, float* __restrict__ Z)
{
    const int ss = blockIdx.x >> 4;
    const int tt0 = (blockIdx.x & 15) * 4;
    const int tid = threadIdx.x;
    const int w = tid >> 6, lane = tid & 63;

    __shared__ float th_s[4][64], u_s[4][64], d_s[4][16];
    __shared__ float es[4][32], et[4][64], w10[4][10];

    {   // load per-row vectors: wave w serves row tt0+w
        const size_t r = (size_t)(tt0 + w) * 32 + ss;
        th_s[w][lane] = th[r * 64 + lane];
        u_s[w][lane]  = uu[r * 64 + lane];
        if (lane < 16) d_s[w][lane] = dd[r * 16 + lane];
    }
    __syncthreads();

    // ---- Phase A: temporal scores (all waves; wave w -> row tt0+w, lane=t)
    {
        const int t = lane;
        const float4* xp = (const float4*)(xph + ((size_t)t * 32 + ss) * 64);
        const float4* tv4 = (const float4*)th_s[w];
        float sc = 0.f;
#pragma unroll
        for (int a = 0; a < 16; ++a) sc += dot4(xp[a], tv4[a]);
        const float2* tp = (const float2*)(temp + (((size_t)(tt0 + w) * 64 + t) * 32 + ss) * 10);
        const float2* dv = (const float2*)d_s[w];
        float2 tmpv[5];
#pragma unroll
        for (int q = 0; q < 5; ++q) {
            tmpv[q] = tp[q];
            const float2 d2 = dv[q];
            sc += tmpv[q].x * d2.x + tmpv[q].y * d2.y;
        }
        float m = sc;
#pragma unroll
        for (int off = 32; off; off >>= 1) m = fmaxf(m, __shfl_xor(m, off));
        const float e = __expf(sc - m);
        float s = e;
#pragma unroll
        for (int off = 32; off; off >>= 1) s += __shfl_xor(s, off);
        const float at = e / s;
        et[w][t] = at;
        // fused w10: lane-local weighted temp, butterfly-reduce 10 components
        float r10[10];
#pragma unroll
        for (int q = 0; q < 5; ++q) { r10[2 * q] = at * tmpv[q].x; r10[2 * q + 1] = at * tmpv[q].y; }
#pragma unroll
        for (int off = 32; off; off >>= 1) {
#pragma unroll
            for (int i = 0; i < 10; ++i) r10[i] += __shfl_xor(r10[i], off);
        }
        if (lane == 0) {
#pragma unroll
            for (int i = 0; i < 10; ++i) w10[w][i] = r10[i];
        }
    }

    // ---- Phase A: spatial scores (waves 0-1: thread = ttl*32 + k)
    if (tid < 128) {
        const int ttl = tid >> 5, k = tid & 31;
        const float4* xp = (const float4*)(xph + ((size_t)(tt0 + ttl) * 32 + k) * 64);
        const float4* pp = (const float4*)(pos + ((size_t)ss * 32 + k) * 64);
        const float4* tv4 = (const float4*)th_s[ttl];
        const float4* uv4 = (const float4*)u_s[ttl];
        float sc = 0.f;
#pragma unroll
        for (int a = 0; a < 16; ++a) sc += dot4(xp[a], tv4[a]) + dot4(pp[a], uv4[a]);
        float m = sc;
#pragma unroll
        for (int off = 16; off; off >>= 1) m = fmaxf(m, __shfl_xor(m, off));
        const float e = __expf(sc - m);
        float s = e;
#pragma unroll
        for (int off = 16; off; off >>= 1) s += __shfl_xor(s, off);
        es[ttl][k] = e / s;
    }
    __syncthreads();

    // ---- Phase B: xc for 4 rows, one f per thread ----
    {
        const int f = tid;
        float acc0 = 0.f, acc1 = 0.f, acc2 = 0.f, acc3 = 0.f;
        const float* bt = bd + (size_t)ss * 256 + f;
#pragma unroll 4
        for (int t = 0; t < 64; ++t) {
            const float xv = bt[(size_t)t * 32 * 256];   // shared by 4 rows
            acc0 += et[0][t] * xv; acc1 += et[1][t] * xv;
            acc2 += et[2][t] * xv; acc3 += et[3][t] * xv;
        }
        float sa[4] = {acc0, acc1, acc2, acc3};
#pragma unroll
        for (int ttl = 0; ttl < 4; ++ttl) {
            const float* bs = bd + (size_t)(tt0 + ttl) * 32 * 256 + f;
            float a2 = 0.f;
#pragma unroll 4
            for (int k = 0; k < 32; ++k) a2 += es[ttl][k] * bs[(size_t)k * 256];
            Z[((size_t)(tt0 + ttl) * 32 + ss) * 320 + f] = sa[ttl] + a2;
        }
    }

    // ---- Phase C: pv + gsum (wave w -> row tt0+w, lane = p) ----
    {
        const int p = lane;
        const float* pb = pos + (size_t)ss * 32 * 64 + p;
        float pv = 0.f;
#pragma unroll 4
        for (int k = 0; k < 32; ++k) pv += es[w][k] * pb[(size_t)k * 64];
        float g = pv + btmp[p];
#pragma unroll
        for (int q = 0; q < 10; ++q) g += w10[w][q] * Wtmp[q * 64 + p];
        Z[((size_t)(tt0 + w) * 32 + ss) * 320 + 256 + p] = g;
    }
}

// ---------------------------------------------------------------------------
// K3: out[r,f] = Z[r,:]@Wg[:,f] + 2*bg[f].  8 rows per block; Wg coalesced,
// reused across rows; Z reads wave-uniform (scalar loads).
// ---------------------------------------------------------------------------
__global__ __launch_bounds__(256) void k_out(
    const float* __restrict__ Z, const float* __restrict__ Wg,
    const float* __restrict__ bg, float* __restrict__ out)
{
    const int f = threadIdx.x;
    const int r0 = blockIdx.x * 8;
    const float* z0 = Z + (size_t)r0 * 320;
    float acc[8] = {0.f, 0.f, 0.f, 0.f, 0.f, 0.f, 0.f, 0.f};
#pragma unroll 4
    for (int k = 0; k < 320; ++k) {
        const float wv = Wg[(size_t)k * 256 + f];
#pragma unroll
        for (int j = 0; j < 8; ++j) acc[j] += z0[(size_t)j * 320 + k] * wv;
    }
    const float b2 = 2.f * bg[f];
#pragma unroll
    for (int j = 0; j < 8; ++j) out[(size_t)(r0 + j) * 256 + f] = acc[j] + b2;
}

extern "C" void kernel_launch(void* const* d_in, const int* in_sizes, int n_in,
                              void* d_out, int out_size, void* d_ws, size_t ws_size,
                              hipStream_t stream) {
    const float* bd   = (const float*)d_in[0];
    const float* positions = (const float*)d_in[1];
    const float* temp = (const float*)d_in[2];
    const float* Wa   = (const float*)d_in[3];
    const float* ba   = (const float*)d_in[4];
    const float* Wb   = (const float*)d_in[5];
    // d_in[6] = bb: constant shift inside both softmaxes; cancels
    const float* Wg   = (const float*)d_in[7];
    const float* bg   = (const float*)d_in[8];
    const float* Wpos = (const float*)d_in[9];
    const float* bpos = (const float*)d_in[10];
    const float* Wtmp = (const float*)d_in[11];
    const float* btmp = (const float*)d_in[12];
    float* out = (float*)d_out;

    float* ws  = (float*)d_ws;
    float* xph = ws + OFF_XPH;
    float* th  = ws + OFF_TH;
    float* uu  = ws + OFF_UU;
    float* dd  = ws + OFF_DD;
    float* pos = ws + OFF_POS;
    float* Z   = ws + OFF_Z;

    k_pre<<<512, 256, 0, stream>>>(bd, Wa, ba, Wb, Wtmp, positions, Wpos, bpos,
                                   xph, th, uu, dd, pos);
    k_attn<<<512, 256, 0, stream>>>(bd, temp, Wtmp, btmp, xph, th, uu, dd, pos, Z);
    k_out<<<R / 8, 256, 0, stream>>>(Z, Wg, bg, out);
}

// Round 5
// 122.614 us; speedup vs baseline: 1.7322x; 1.2140x over previous
//
#include <hip/hip_runtime.h>

constexpr int T = 64, S = 32, F = 256, A = 64;
constexpr int R = T * S;  // 2048

// workspace layout (fp32 elements)
constexpr size_t OFF_XPH = 0;                           // R*A
constexpr size_t OFF_TH  = OFF_XPH + (size_t)R * A;     // R*A
constexpr size_t OFF_UU  = OFF_TH  + (size_t)R * A;     // R*A
constexpr size_t OFF_DD  = OFF_UU  + (size_t)R * A;     // R*16
constexpr size_t OFF_POS = OFF_DD  + (size_t)R * 16;    // S*S*64
constexpr size_t OFF_Z   = OFF_POS + (size_t)S * S * 64;// R*320

__device__ __forceinline__ float dot4(float4 a, float4 b) {
    return a.x * b.x + a.y * b.y + a.z * b.z + a.w * b.w;
}

// ---------------------------------------------------------------------------
// K1: blocks 0..255: 8 x-rows each (2 rows per wave).
//   th = x@Wa + ba, xph = x@WbX   (fused c-loop: 1 Wa + 1 Wb load -> 4 FMA)
//   uu = WbP@th, dd = Wtmp@uu
// blocks 256..511: pos[j,k,p] = concat(positions[e]@Wpos + bpos)
// ---------------------------------------------------------------------------
__global__ __launch_bounds__(256) void k_pre(
    const float* __restrict__ bd, const float* __restrict__ Wa,
    const float* __restrict__ ba, const float* __restrict__ Wb,
    const float* __restrict__ Wtmp, const float* __restrict__ positions,
    const float* __restrict__ Wpos, const float* __restrict__ bpos,
    float* __restrict__ xph, float* __restrict__ th,
    float* __restrict__ uu, float* __restrict__ dd, float* __restrict__ pos)
{
    const int blk = blockIdx.x;
    const int tid = threadIdx.x;

    if (blk >= 256) {  // ---- pos blocks ----
        const int idx = (blk - 256) * 256 + tid;   // (j*32+k)*64 + p
        const int p = idx & 63, jk = idx >> 6;
        const int e = p >> 5, pp = p & 31;
        const float* src = positions + (size_t)(e * 1024 + jk) * 9;
        float acc = bpos[pp];
#pragma unroll
        for (int q = 0; q < 9; ++q) acc += src[q] * Wpos[q * 32 + pp];
        pos[idx] = acc;
        return;
    }

    __shared__ float xs[8 * 256];
    __shared__ float ths[8][64];
    __shared__ float us[8][64];
    const int w = tid >> 6, lane = tid & 63;
    const int row0 = blk * 8 + 2 * w;          // this wave's two rows

    {   // stage 8 rows of x: 512 float4s over 256 threads
        const float4* src = (const float4*)(bd + (size_t)blk * 8 * 256);
        float4* dst = (float4*)xs;
        dst[tid] = src[tid];
        dst[tid + 256] = src[tid + 256];
    }
    __syncthreads();

    const float* x0 = xs + (2 * w) * 256;
    const float* x1 = xs + (2 * w + 1) * 256;
    float accA0 = ba[lane], accA1 = accA0, accB0 = 0.f, accB1 = 0.f;
#pragma unroll
    for (int c0 = 0; c0 < 256; c0 += 8) {
        float wa[8], wb[8];
#pragma unroll
        for (int j = 0; j < 8; ++j) wa[j] = Wa[(c0 + j) * 64 + lane];
#pragma unroll
        for (int j = 0; j < 8; ++j) wb[j] = Wb[(c0 + j) * 64 + lane];
#pragma unroll
        for (int j = 0; j < 8; ++j) {
            const float xa = x0[c0 + j], xb = x1[c0 + j];
            accA0 += xa * wa[j]; accA1 += xb * wa[j];
            accB0 += xa * wb[j]; accB1 += xb * wb[j];
        }
    }
    th[(size_t)row0 * 64 + lane] = accA0;
    th[(size_t)(row0 + 1) * 64 + lane] = accA1;
    xph[(size_t)row0 * 64 + lane] = accB0;
    xph[(size_t)(row0 + 1) * 64 + lane] = accB1;
    ths[2 * w][lane] = accA0; ths[2 * w + 1][lane] = accA1;
    __syncthreads();

    float accU0 = 0.f, accU1 = 0.f;
#pragma unroll 8
    for (int a = 0; a < 64; ++a) {
        const float wp = Wb[(256 + lane) * 64 + a];
        accU0 += ths[2 * w][a] * wp;
        accU1 += ths[2 * w + 1][a] * wp;
    }
    uu[(size_t)row0 * 64 + lane] = accU0;
    uu[(size_t)(row0 + 1) * 64 + lane] = accU1;
    us[2 * w][lane] = accU0; us[2 * w + 1][lane] = accU1;
    __syncthreads();

    const int rsel = lane >> 4, q = lane & 15;
    if (rsel < 2 && q < 10) {
        float accD = 0.f;
#pragma unroll 8
        for (int p2 = 0; p2 < 64; ++p2) accD += us[2 * w + rsel][p2] * Wtmp[q * 64 + p2];
        dd[(size_t)(row0 + rsel) * 16 + q] = accD;
    }
}

// ---------------------------------------------------------------------------
// K2: one block per (ss, 4 consecutive tt).  blockIdx = ss*16 + tt0/4.
// Phase A: all 4 waves temporal scores; softmax + w10 fused via butterflies.
//          waves 0-1 spatial scores.
// Phase B: xc for 4 rows, temporal bd loads shared, 8-deep load pipelining.
// Phase C: pv + gsum per wave.  2 barriers total.
// ---------------------------------------------------------------------------
__global__ __launch_bounds__(256) void k_attn(
    const float* __restrict__ bd, const float* __restrict__ temp,
    const float* __restrict__ Wtmp, const float* __restrict__ btmp,
    const float* __restrict__ xph, const float* __restrict__ th,
    const float* __restrict__ uu, const float* __restrict__ dd,
    const float* __restrict__ pos, float* __restrict__ Z)
{
    const int ss = blockIdx.x >> 4;
    const int tt0 = (blockIdx.x & 15) * 4;
    const int tid = threadIdx.x;
    const int w = tid >> 6, lane = tid & 63;

    __shared__ float th_s[4][64], u_s[4][64], d_s[4][16];
    __shared__ float es[4][32], et[4][64], w10[4][10];

    {   // load per-row vectors: wave w serves row tt0+w
        const size_t r = (size_t)(tt0 + w) * 32 + ss;
        th_s[w][lane] = th[r * 64 + lane];
        u_s[w][lane]  = uu[r * 64 + lane];
        if (lane < 16) d_s[w][lane] = dd[r * 16 + lane];
    }
    __syncthreads();

    // ---- Phase A: temporal scores (all waves; wave w -> row tt0+w, lane=t)
    {
        const int t = lane;
        const float4* xp = (const float4*)(xph + ((size_t)t * 32 + ss) * 64);
        const float4* tv4 = (const float4*)th_s[w];
        float sc = 0.f;
#pragma unroll
        for (int a = 0; a < 16; ++a) sc += dot4(xp[a], tv4[a]);
        const float2* tp = (const float2*)(temp + (((size_t)(tt0 + w) * 64 + t) * 32 + ss) * 10);
        const float2* dv = (const float2*)d_s[w];
        float2 tmpv[5];
#pragma unroll
        for (int q = 0; q < 5; ++q) {
            tmpv[q] = tp[q];
            const float2 d2 = dv[q];
            sc += tmpv[q].x * d2.x + tmpv[q].y * d2.y;
        }
        float m = sc;
#pragma unroll
        for (int off = 32; off; off >>= 1) m = fmaxf(m, __shfl_xor(m, off));
        const float e = __expf(sc - m);
        float s = e;
#pragma unroll
        for (int off = 32; off; off >>= 1) s += __shfl_xor(s, off);
        const float at = e / s;
        et[w][t] = at;
        float r10[10];
#pragma unroll
        for (int q = 0; q < 5; ++q) { r10[2 * q] = at * tmpv[q].x; r10[2 * q + 1] = at * tmpv[q].y; }
#pragma unroll
        for (int off = 32; off; off >>= 1) {
#pragma unroll
            for (int i = 0; i < 10; ++i) r10[i] += __shfl_xor(r10[i], off);
        }
        if (lane == 0) {
#pragma unroll
            for (int i = 0; i < 10; ++i) w10[w][i] = r10[i];
        }
    }

    // ---- Phase A: spatial scores (waves 0-1: thread = ttl*32 + k)
    if (tid < 128) {
        const int ttl = tid >> 5, k = tid & 31;
        const float4* xp = (const float4*)(xph + ((size_t)(tt0 + ttl) * 32 + k) * 64);
        const float4* pp = (const float4*)(pos + ((size_t)ss * 32 + k) * 64);
        const float4* tv4 = (const float4*)th_s[ttl];
        const float4* uv4 = (const float4*)u_s[ttl];
        float sc = 0.f;
#pragma unroll
        for (int a = 0; a < 16; ++a) sc += dot4(xp[a], tv4[a]) + dot4(pp[a], uv4[a]);
        float m = sc;
#pragma unroll
        for (int off = 16; off; off >>= 1) m = fmaxf(m, __shfl_xor(m, off));
        const float e = __expf(sc - m);
        float s = e;
#pragma unroll
        for (int off = 16; off; off >>= 1) s += __shfl_xor(s, off);
        es[ttl][k] = e / s;
    }
    __syncthreads();

    // ---- Phase B: xc for 4 rows, one f per thread, 8-deep load batches ----
    {
        const int f = tid;
        float acc0 = 0.f, acc1 = 0.f, acc2 = 0.f, acc3 = 0.f;
        const float* bt = bd + (size_t)ss * 256 + f;
#pragma unroll
        for (int t0 = 0; t0 < 64; t0 += 8) {
            float xv[8];
#pragma unroll
            for (int j = 0; j < 8; ++j) xv[j] = bt[(size_t)(t0 + j) * 32 * 256];
#pragma unroll
            for (int j = 0; j < 8; ++j) {
                acc0 += et[0][t0 + j] * xv[j]; acc1 += et[1][t0 + j] * xv[j];
                acc2 += et[2][t0 + j] * xv[j]; acc3 += et[3][t0 + j] * xv[j];
            }
        }
        float sa[4] = {acc0, acc1, acc2, acc3};
#pragma unroll
        for (int ttl = 0; ttl < 4; ++ttl) {
            const float* bs = bd + (size_t)(tt0 + ttl) * 32 * 256 + f;
            float a2 = 0.f;
#pragma unroll
            for (int k0 = 0; k0 < 32; k0 += 8) {
                float yv[8];
#pragma unroll
                for (int j = 0; j < 8; ++j) yv[j] = bs[(size_t)(k0 + j) * 256];
#pragma unroll
                for (int j = 0; j < 8; ++j) a2 += es[ttl][k0 + j] * yv[j];
            }
            Z[((size_t)(tt0 + ttl) * 32 + ss) * 320 + f] = sa[ttl] + a2;
        }
    }

    // ---- Phase C: pv + gsum (wave w -> row tt0+w, lane = p) ----
    {
        const int p = lane;
        const float* pb = pos + (size_t)ss * 32 * 64 + p;
        float pv = 0.f;
#pragma unroll
        for (int k0 = 0; k0 < 32; k0 += 8) {
            float yv[8];
#pragma unroll
            for (int j = 0; j < 8; ++j) yv[j] = pb[(size_t)(k0 + j) * 64];
#pragma unroll
            for (int j = 0; j < 8; ++j) pv += es[w][k0 + j] * yv[j];
        }
        float g = pv + btmp[p];
#pragma unroll
        for (int q = 0; q < 10; ++q) g += w10[w][q] * Wtmp[q * 64 + p];
        Z[((size_t)(tt0 + w) * 32 + ss) * 320 + 256 + p] = g;
    }
}

// ---------------------------------------------------------------------------
// K3: out[r,f] = Z[r,:]@Wg[:,f] + 2*bg[f].  4 rows per block, 512 blocks
// (2 blocks/CU -> 2 waves/SIMD for latency hiding); Wg coalesced + L2-hot,
// Z reads wave-uniform (scalar loads); 4-deep independent load batches.
// ---------------------------------------------------------------------------
__global__ __launch_bounds__(256) void k_out(
    const float* __restrict__ Z, const float* __restrict__ Wg,
    const float* __restrict__ bg, float* __restrict__ out)
{
    const int f = threadIdx.x;
    const int r0 = blockIdx.x * 4;
    const float* z0 = Z + (size_t)r0 * 320;
    float acc[4] = {0.f, 0.f, 0.f, 0.f};
#pragma unroll
    for (int k0 = 0; k0 < 320; k0 += 4) {
        float wv[4];
#pragma unroll
        for (int j = 0; j < 4; ++j) wv[j] = Wg[(size_t)(k0 + j) * 256 + f];
#pragma unroll
        for (int j = 0; j < 4; ++j) {
#pragma unroll
            for (int r = 0; r < 4; ++r) acc[r] += z0[(size_t)r * 320 + k0 + j] * wv[j];
        }
    }
    const float b2 = 2.f * bg[f];
#pragma unroll
    for (int r = 0; r < 4; ++r) out[(size_t)(r0 + r) * 256 + f] = acc[r] + b2;
}

extern "C" void kernel_launch(void* const* d_in, const int* in_sizes, int n_in,
                              void* d_out, int out_size, void* d_ws, size_t ws_size,
                              hipStream_t stream) {
    const float* bd   = (const float*)d_in[0];
    const float* positions = (const float*)d_in[1];
    const float* temp = (const float*)d_in[2];
    const float* Wa   = (const float*)d_in[3];
    const float* ba   = (const float*)d_in[4];
    const float* Wb   = (const float*)d_in[5];
    // d_in[6] = bb: constant shift inside both softmaxes; cancels
    const float* Wg   = (const float*)d_in[7];
    const float* bg   = (const float*)d_in[8];
    const float* Wpos = (const float*)d_in[9];
    const float* bpos = (const float*)d_in[10];
    const float* Wtmp = (const float*)d_in[11];
    const float* btmp = (const float*)d_in[12];
    float* out = (float*)d_out;

    float* ws  = (float*)d_ws;
    float* xph = ws + OFF_XPH;
    float* th  = ws + OFF_TH;
    float* uu  = ws + OFF_UU;
    float* dd  = ws + OFF_DD;
    float* pos = ws + OFF_POS;
    float* Z   = ws + OFF_Z;

    k_pre<<<512, 256, 0, stream>>>(bd, Wa, ba, Wb, Wtmp, positions, Wpos, bpos,
                                   xph, th, uu, dd, pos);
    k_attn<<<512, 256, 0, stream>>>(bd, temp, Wtmp, btmp, xph, th, uu, dd, pos, Z);
    k_out<<<512, 256, 0, stream>>>(Z, Wg, bg, out);
}

// Round 6
// 116.433 us; speedup vs baseline: 1.8242x; 1.0531x over previous
//
#include <hip/hip_runtime.h>

constexpr int T = 64, S = 32, F = 256, A = 64;
constexpr int R = T * S;  // 2048

// workspace layout (fp32 elements)
constexpr size_t OFF_XPH = 0;                           // R*A
constexpr size_t OFF_TH  = OFF_XPH + (size_t)R * A;     // R*A
constexpr size_t OFF_UU  = OFF_TH  + (size_t)R * A;     // R*A
constexpr size_t OFF_DD  = OFF_UU  + (size_t)R * A;     // R*16
constexpr size_t OFF_POS = OFF_DD  + (size_t)R * 16;    // S*S*64

__device__ __forceinline__ float dot4(float4 a, float4 b) {
    return a.x * b.x + a.y * b.y + a.z * b.z + a.w * b.w;
}
__device__ __forceinline__ float4 f4fma(float s, float4 v, float4 a) {
    a.x += s * v.x; a.y += s * v.y; a.z += s * v.z; a.w += s * v.w; return a;
}
__device__ __forceinline__ float4 f4add(float4 a, float4 b) {
    a.x += b.x; a.y += b.y; a.z += b.z; a.w += b.w; return a;
}

// ---------------------------------------------------------------------------
// K1: blocks 0..255: 8 x-rows each (2 rows per wave).
//   th = x@Wa + ba, xph = x@WbX, uu = WbP@th, dd = Wtmp@uu
// blocks 256..511: pos[j,k,p] = concat(positions[e]@Wpos + bpos)
// ---------------------------------------------------------------------------
__global__ __launch_bounds__(256) void k_pre(
    const float* __restrict__ bd, const float* __restrict__ Wa,
    const float* __restrict__ ba, const float* __restrict__ Wb,
    const float* __restrict__ Wtmp, const float* __restrict__ positions,
    const float* __restrict__ Wpos, const float* __restrict__ bpos,
    float* __restrict__ xph, float* __restrict__ th,
    float* __restrict__ uu, float* __restrict__ dd, float* __restrict__ pos)
{
    const int blk = blockIdx.x;
    const int tid = threadIdx.x;

    if (blk >= 256) {  // ---- pos blocks ----
        const int idx = (blk - 256) * 256 + tid;   // (j*32+k)*64 + p
        const int p = idx & 63, jk = idx >> 6;
        const int e = p >> 5, pp = p & 31;
        const float* src = positions + (size_t)(e * 1024 + jk) * 9;
        float acc = bpos[pp];
#pragma unroll
        for (int q = 0; q < 9; ++q) acc += src[q] * Wpos[q * 32 + pp];
        pos[idx] = acc;
        return;
    }

    __shared__ float xs[8 * 256];
    __shared__ float ths[8][64];
    __shared__ float us[8][64];
    const int w = tid >> 6, lane = tid & 63;
    const int row0 = blk * 8 + 2 * w;          // this wave's two rows

    {   // stage 8 rows of x: 512 float4s over 256 threads
        const float4* src = (const float4*)(bd + (size_t)blk * 8 * 256);
        float4* dst = (float4*)xs;
        dst[tid] = src[tid];
        dst[tid + 256] = src[tid + 256];
    }
    __syncthreads();

    const float* x0 = xs + (2 * w) * 256;
    const float* x1 = xs + (2 * w + 1) * 256;
    float accA0 = ba[lane], accA1 = accA0, accB0 = 0.f, accB1 = 0.f;
#pragma unroll
    for (int c0 = 0; c0 < 256; c0 += 8) {
        float wa[8], wb[8];
#pragma unroll
        for (int j = 0; j < 8; ++j) wa[j] = Wa[(c0 + j) * 64 + lane];
#pragma unroll
        for (int j = 0; j < 8; ++j) wb[j] = Wb[(c0 + j) * 64 + lane];
#pragma unroll
        for (int j = 0; j < 8; ++j) {
            const float xa = x0[c0 + j], xb = x1[c0 + j];
            accA0 += xa * wa[j]; accA1 += xb * wa[j];
            accB0 += xa * wb[j]; accB1 += xb * wb[j];
        }
    }
    th[(size_t)row0 * 64 + lane] = accA0;
    th[(size_t)(row0 + 1) * 64 + lane] = accA1;
    xph[(size_t)row0 * 64 + lane] = accB0;
    xph[(size_t)(row0 + 1) * 64 + lane] = accB1;
    ths[2 * w][lane] = accA0; ths[2 * w + 1][lane] = accA1;
    __syncthreads();

    float accU0 = 0.f, accU1 = 0.f;
#pragma unroll 8
    for (int a = 0; a < 64; ++a) {
        const float wp = Wb[(256 + lane) * 64 + a];
        accU0 += ths[2 * w][a] * wp;
        accU1 += ths[2 * w + 1][a] * wp;
    }
    uu[(size_t)row0 * 64 + lane] = accU0;
    uu[(size_t)(row0 + 1) * 64 + lane] = accU1;
    us[2 * w][lane] = accU0; us[2 * w + 1][lane] = accU1;
    __syncthreads();

    const int rsel = lane >> 4, q = lane & 15;
    if (rsel < 2 && q < 10) {
        float accD = 0.f;
#pragma unroll 8
        for (int p2 = 0; p2 < 64; ++p2) accD += us[2 * w + rsel][p2] * Wtmp[q * 64 + p2];
        dd[(size_t)(row0 + rsel) * 16 + q] = accD;
    }
}

// ---------------------------------------------------------------------------
// K2 (fused attn + output GEMV): one block per (ss, 4 consecutive tt).
//   Phase A: temporal scores (wave w = row w) + spatial scores (waves 0-1);
//            softmax + w10 fused via shuffle butterflies.
//   Phase C: gsum -> zz[r][256..319]
//   Temporal xc: t split across waves, f in float4 (1 KiB/wave-inst),
//                cross-wave reduce via LDS part4.
//   Spatial xc:  wave w owns row w, float4 f; combine -> zz[r][0..255]
//   Epilogue:    out[r] = zz[r]@Wg + 2bg; k split across waves (80 each),
//                float4 f, cross-wave reduce, float4 store.
// ---------------------------------------------------------------------------
__global__ __launch_bounds__(256) void k_fuse(
    const float* __restrict__ bd, const float* __restrict__ temp,
    const float* __restrict__ Wtmp, const float* __restrict__ btmp,
    const float* __restrict__ Wg, const float* __restrict__ bg,
    const float* __restrict__ xph, const float* __restrict__ th,
    const float* __restrict__ uu, const float* __restrict__ dd,
    const float* __restrict__ pos, float* __restrict__ out)
{
    const int ss = blockIdx.x >> 4;
    const int tt0 = (blockIdx.x & 15) * 4;
    const int tid = threadIdx.x;
    const int w = tid >> 6, lane = tid & 63;

    __shared__ float th_s[4][64], u_s[4][64], d_s[4][16];
    __shared__ float es[4][32], et[4][64], w10[4][10];
    __shared__ float zz[4][320];          // [row][xc(256) | gsum(64)]
    __shared__ float4 part4[4][4][64];    // [src wave][row][f4]

    {   // per-row vectors: wave w serves row tt0+w
        const size_t r = (size_t)(tt0 + w) * 32 + ss;
        th_s[w][lane] = th[r * 64 + lane];
        u_s[w][lane]  = uu[r * 64 + lane];
        if (lane < 16) d_s[w][lane] = dd[r * 16 + lane];
    }
    __syncthreads();   // A

    // ---- Phase A: temporal scores (wave w -> row tt0+w, lane = t) ----
    {
        const int t = lane;
        const float4* xp = (const float4*)(xph + ((size_t)t * 32 + ss) * 64);
        const float4* tv4 = (const float4*)th_s[w];
        float sc = 0.f;
#pragma unroll
        for (int a = 0; a < 16; ++a) sc += dot4(xp[a], tv4[a]);
        const float2* tp = (const float2*)(temp + (((size_t)(tt0 + w) * 64 + t) * 32 + ss) * 10);
        const float2* dv = (const float2*)d_s[w];
        float2 tmpv[5];
#pragma unroll
        for (int q = 0; q < 5; ++q) {
            tmpv[q] = tp[q];
            const float2 d2 = dv[q];
            sc += tmpv[q].x * d2.x + tmpv[q].y * d2.y;
        }
        float m = sc;
#pragma unroll
        for (int off = 32; off; off >>= 1) m = fmaxf(m, __shfl_xor(m, off));
        const float e = __expf(sc - m);
        float s = e;
#pragma unroll
        for (int off = 32; off; off >>= 1) s += __shfl_xor(s, off);
        const float at = e / s;
        et[w][t] = at;
        float r10[10];
#pragma unroll
        for (int q = 0; q < 5; ++q) { r10[2 * q] = at * tmpv[q].x; r10[2 * q + 1] = at * tmpv[q].y; }
#pragma unroll
        for (int off = 32; off; off >>= 1) {
#pragma unroll
            for (int i = 0; i < 10; ++i) r10[i] += __shfl_xor(r10[i], off);
        }
        if (lane == 0) {
#pragma unroll
            for (int i = 0; i < 10; ++i) w10[w][i] = r10[i];
        }
    }

    // ---- Phase A: spatial scores (waves 0-1: thread = ttl*32 + k) ----
    if (tid < 128) {
        const int ttl = tid >> 5, k = tid & 31;
        const float4* xp = (const float4*)(xph + ((size_t)(tt0 + ttl) * 32 + k) * 64);
        const float4* pp = (const float4*)(pos + ((size_t)ss * 32 + k) * 64);
        const float4* tv4 = (const float4*)th_s[ttl];
        const float4* uv4 = (const float4*)u_s[ttl];
        float sc = 0.f;
#pragma unroll
        for (int a = 0; a < 16; ++a) sc += dot4(xp[a], tv4[a]) + dot4(pp[a], uv4[a]);
        float m = sc;
#pragma unroll
        for (int off = 16; off; off >>= 1) m = fmaxf(m, __shfl_xor(m, off));
        const float e = __expf(sc - m);
        float s = e;
#pragma unroll
        for (int off = 16; off; off >>= 1) s += __shfl_xor(s, off);
        es[ttl][k] = e / s;
    }
    __syncthreads();   // B

    // ---- Phase C: gsum -> zz[w][256+p]  (wave w -> row w, lane = p) ----
    {
        const int p = lane;
        const float* pb = pos + (size_t)ss * 32 * 64 + p;
        float pv = 0.f;
#pragma unroll
        for (int k0 = 0; k0 < 32; k0 += 8) {
            float yv[8];
#pragma unroll
            for (int j = 0; j < 8; ++j) yv[j] = pb[(size_t)(k0 + j) * 64];
#pragma unroll
            for (int j = 0; j < 8; ++j) pv += es[w][k0 + j] * yv[j];
        }
        float g = pv + btmp[p];
#pragma unroll
        for (int q = 0; q < 10; ++q) g += w10[w][q] * Wtmp[q * 64 + p];
        zz[w][256 + p] = g;
    }

    // ---- temporal xc partials: wave w covers t in [16w, 16w+16), f4 = lane
    {
        const float4* bd4 = (const float4*)bd;
        float4 acc[4];
#pragma unroll
        for (int r = 0; r < 4; ++r) acc[r] = make_float4(0.f, 0.f, 0.f, 0.f);
#pragma unroll
        for (int j = 0; j < 16; ++j) {
            const int t = 16 * w + j;
            const float4 x4 = bd4[((size_t)t * 32 + ss) * 64 + lane];
#pragma unroll
            for (int r = 0; r < 4; ++r) acc[r] = f4fma(et[r][t], x4, acc[r]);
        }
#pragma unroll
        for (int r = 0; r < 4; ++r) part4[w][r][lane] = acc[r];
    }
    __syncthreads();   // C

    // ---- spatial xc + combine: wave w owns row w, f4 = lane ----
    {
        const float4* bd4 = (const float4*)bd;
        float4 a = make_float4(0.f, 0.f, 0.f, 0.f);
#pragma unroll
        for (int k = 0; k < 32; ++k) {
            const float4 x4 = bd4[((size_t)(tt0 + w) * 32 + k) * 64 + lane];
            a = f4fma(es[w][k], x4, a);
        }
#pragma unroll
        for (int w2 = 0; w2 < 4; ++w2) a = f4add(a, part4[w2][w][lane]);
        ((float4*)&zz[w][0])[lane] = a;
    }
    __syncthreads();   // D

    // ---- epilogue: out = zz@Wg + 2bg; wave w covers k in [80w, 80w+80) ----
    {
        const float4* Wg4 = (const float4*)Wg;
        float4 acc[4];
#pragma unroll
        for (int r = 0; r < 4; ++r) acc[r] = make_float4(0.f, 0.f, 0.f, 0.f);
        const int kbase = 80 * w;
#pragma unroll 4
        for (int j = 0; j < 20; ++j) {
            const int k0 = kbase + 4 * j;
            float4 wg[4];
#pragma unroll
            for (int q = 0; q < 4; ++q) wg[q] = Wg4[(size_t)(k0 + q) * 64 + lane];
#pragma unroll
            for (int r = 0; r < 4; ++r) {
                const float4 zv = *(const float4*)&zz[r][k0];
                acc[r] = f4fma(zv.x, wg[0], acc[r]);
                acc[r] = f4fma(zv.y, wg[1], acc[r]);
                acc[r] = f4fma(zv.z, wg[2], acc[r]);
                acc[r] = f4fma(zv.w, wg[3], acc[r]);
            }
        }
#pragma unroll
        for (int r = 0; r < 4; ++r) part4[w][r][lane] = acc[r];
    }
    __syncthreads();   // E

    // ---- final cross-wave reduce + store: wave w stores row tt0+w ----
    {
        float4 o = part4[0][w][lane];
        o = f4add(o, part4[1][w][lane]);
        o = f4add(o, part4[2][w][lane]);
        o = f4add(o, part4[3][w][lane]);
        const float4 b4 = ((const float4*)bg)[lane];
        o.x += 2.f * b4.x; o.y += 2.f * b4.y; o.z += 2.f * b4.z; o.w += 2.f * b4.w;
        ((float4*)out)[((size_t)(tt0 + w) * 32 + ss) * 64 + lane] = o;
    }
}

extern "C" void kernel_launch(void* const* d_in, const int* in_sizes, int n_in,
                              void* d_out, int out_size, void* d_ws, size_t ws_size,
                              hipStream_t stream) {
    const float* bd   = (const float*)d_in[0];
    const float* positions = (const float*)d_in[1];
    const float* temp = (const float*)d_in[2];
    const float* Wa   = (const float*)d_in[3];
    const float* ba   = (const float*)d_in[4];
    const float* Wb   = (const float*)d_in[5];
    // d_in[6] = bb: constant shift inside both softmaxes; cancels
    const float* Wg   = (const float*)d_in[7];
    const float* bg   = (const float*)d_in[8];
    const float* Wpos = (const float*)d_in[9];
    const float* bpos = (const float*)d_in[10];
    const float* Wtmp = (const float*)d_in[11];
    const float* btmp = (const float*)d_in[12];
    float* out = (float*)d_out;

    float* ws  = (float*)d_ws;
    float* xph = ws + OFF_XPH;
    float* th  = ws + OFF_TH;
    float* uu  = ws + OFF_UU;
    float* dd  = ws + OFF_DD;
    float* pos = ws + OFF_POS;

    k_pre<<<512, 256, 0, stream>>>(bd, Wa, ba, Wb, Wtmp, positions, Wpos, bpos,
                                   xph, th, uu, dd, pos);
    k_fuse<<<512, 256, 0, stream>>>(bd, temp, Wtmp, btmp, Wg, bg,
                                    xph, th, uu, dd, pos, out);
}

// Round 7
// 111.019 us; speedup vs baseline: 1.9132x; 1.0488x over previous
//
#include <hip/hip_runtime.h>
#include <hip/hip_fp16.h>

constexpr int T = 64, S = 32, F = 256, A = 64;
constexpr int R = T * S;  // 2048

// workspace layout (fp32 element units)
constexpr size_t OFF_XPH = 0;                           // R*A
constexpr size_t OFF_TH  = OFF_XPH + (size_t)R * A;     // R*A
constexpr size_t OFF_UU  = OFF_TH  + (size_t)R * A;     // R*A
constexpr size_t OFF_DD  = OFF_UU  + (size_t)R * A;     // R*16
constexpr size_t OFF_POS = OFF_DD  + (size_t)R * 16;    // S*S*64
constexpr size_t OFF_XGH = OFF_POS + (size_t)S * S * 64;// R*F halfs = R*F/2 floats

__device__ __forceinline__ float dot4(float4 a, float4 b) {
    return a.x * b.x + a.y * b.y + a.z * b.z + a.w * b.w;
}
__device__ __forceinline__ float4 f4fma(float s, float4 v, float4 a) {
    a.x += s * v.x; a.y += s * v.y; a.z += s * v.z; a.w += s * v.w; return a;
}
__device__ __forceinline__ float4 f4add(float4 a, float4 b) {
    a.x += b.x; a.y += b.y; a.z += b.z; a.w += b.w; return a;
}
// load 4 halfs (8B coalesced) -> float4
__device__ __forceinline__ float4 ldh4(const __half* p, size_t idx4) {
    float2 raw = ((const float2*)p)[idx4];
    const __half2* h = reinterpret_cast<const __half2*>(&raw);
    const float2 lo = __half22float2(h[0]);
    const float2 hi = __half22float2(h[1]);
    return make_float4(lo.x, lo.y, hi.x, hi.y);
}

// ---------------------------------------------------------------------------
// K1: blocks 0..255: 8 x-rows each (2 rows per wave):
//   th = x@Wa + ba, xph = x@WbX, uu = WbP@th, dd = Wtmp@uu
// blocks 256..511: pos projection (tiny) + XG = x@WgX for 8 rows,
//   stored fp16 (XG feeds only attn-weighted sums; 5e-4 rel err OK).
// ---------------------------------------------------------------------------
__global__ __launch_bounds__(256) void k_pre(
    const float* __restrict__ bd, const float* __restrict__ Wa,
    const float* __restrict__ ba, const float* __restrict__ Wb,
    const float* __restrict__ Wg, const float* __restrict__ Wtmp,
    const float* __restrict__ positions, const float* __restrict__ Wpos,
    const float* __restrict__ bpos,
    float* __restrict__ xph, float* __restrict__ th,
    float* __restrict__ uu, float* __restrict__ dd,
    float* __restrict__ pos, __half* __restrict__ XG_h)
{
    const int blk = blockIdx.x;
    const int tid = threadIdx.x;

    __shared__ float xs[8 * 256];
    __shared__ float ths[8][64];
    __shared__ float us[8][64];

    if (blk >= 256) {  // ---- pos + XG blocks ----
        const int xb = blk - 256;
        {   // pos: idx covers S*S*64 exactly over 256 blocks
            const int idx = xb * 256 + tid;       // (j*32+k)*64 + p
            const int p = idx & 63, jk = idx >> 6;
            const int e = p >> 5, pp = p & 31;
            const float* src = positions + (size_t)(e * 1024 + jk) * 9;
            float acc = bpos[pp];
#pragma unroll
            for (int q = 0; q < 9; ++q) acc += src[q] * Wpos[q * 32 + pp];
            pos[idx] = acc;
        }
        {   // stage 8 x-rows
            const float4* src = (const float4*)(bd + (size_t)xb * 8 * 256);
            float4* dst = (float4*)xs;
            dst[tid] = src[tid];
            dst[tid + 256] = src[tid + 256];
        }
        __syncthreads();
        // XG[r][f] = sum_c x[r][c] * WgX[c][f];  f = tid (coalesced Wg)
        float acc[8] = {0.f, 0.f, 0.f, 0.f, 0.f, 0.f, 0.f, 0.f};
#pragma unroll
        for (int c0 = 0; c0 < 256; c0 += 8) {
            float wv[8];
#pragma unroll
            for (int j = 0; j < 8; ++j) wv[j] = Wg[(size_t)(c0 + j) * 256 + tid];
#pragma unroll
            for (int j = 0; j < 8; ++j) {
#pragma unroll
                for (int r = 0; r < 8; ++r) acc[r] += xs[r * 256 + c0 + j] * wv[j];
            }
        }
#pragma unroll
        for (int r = 0; r < 8; ++r)
            XG_h[(size_t)(xb * 8 + r) * 256 + tid] = __float2half(acc[r]);
        return;
    }

    // ---- row blocks ----
    const int w = tid >> 6, lane = tid & 63;
    const int row0 = blk * 8 + 2 * w;          // this wave's two rows

    {   // stage 8 rows of x
        const float4* src = (const float4*)(bd + (size_t)blk * 8 * 256);
        float4* dst = (float4*)xs;
        dst[tid] = src[tid];
        dst[tid + 256] = src[tid + 256];
    }
    __syncthreads();

    const float* x0 = xs + (2 * w) * 256;
    const float* x1 = xs + (2 * w + 1) * 256;
    float accA0 = ba[lane], accA1 = accA0, accB0 = 0.f, accB1 = 0.f;
#pragma unroll
    for (int c0 = 0; c0 < 256; c0 += 8) {
        float wa[8], wb[8];
#pragma unroll
        for (int j = 0; j < 8; ++j) wa[j] = Wa[(c0 + j) * 64 + lane];
#pragma unroll
        for (int j = 0; j < 8; ++j) wb[j] = Wb[(c0 + j) * 64 + lane];
#pragma unroll
        for (int j = 0; j < 8; ++j) {
            const float xa = x0[c0 + j], xb2 = x1[c0 + j];
            accA0 += xa * wa[j]; accA1 += xb2 * wa[j];
            accB0 += xa * wb[j]; accB1 += xb2 * wb[j];
        }
    }
    th[(size_t)row0 * 64 + lane] = accA0;
    th[(size_t)(row0 + 1) * 64 + lane] = accA1;
    xph[(size_t)row0 * 64 + lane] = accB0;
    xph[(size_t)(row0 + 1) * 64 + lane] = accB1;
    ths[2 * w][lane] = accA0; ths[2 * w + 1][lane] = accA1;
    __syncthreads();

    float accU0 = 0.f, accU1 = 0.f;
#pragma unroll 8
    for (int a = 0; a < 64; ++a) {
        const float wp = Wb[(256 + lane) * 64 + a];
        accU0 += ths[2 * w][a] * wp;
        accU1 += ths[2 * w + 1][a] * wp;
    }
    uu[(size_t)row0 * 64 + lane] = accU0;
    uu[(size_t)(row0 + 1) * 64 + lane] = accU1;
    us[2 * w][lane] = accU0; us[2 * w + 1][lane] = accU1;
    __syncthreads();

    const int rsel = lane >> 4, q = lane & 15;
    if (rsel < 2 && q < 10) {
        float accD = 0.f;
#pragma unroll 8
        for (int p2 = 0; p2 < 64; ++p2) accD += us[2 * w + rsel][p2] * Wtmp[q * 64 + p2];
        dd[(size_t)(row0 + rsel) * 16 + q] = accD;
    }
}

// ---------------------------------------------------------------------------
// K2 (fused): one block per (ss, 4 consecutive tt).  blockIdx = ss*16 + tt0/4.
//   A: temporal scores+softmax+w10 (wave w=row w); spatial scores (waves 0-1)
//   C: gsum -> gs[w][p]; temporal xc partials over fp16 XG (t split by wave)
//   D: spatial xc + temporal combine -> zz4; WgP partials (p split by wave)
//   E: final cross-wave reduce + 2bg + float4 store
// out[r,f] = xcXG[f] + gs[r]@WgP[:,f] + 2bg[f]   (XG = x@WgX precomputed)
// ---------------------------------------------------------------------------
__global__ __launch_bounds__(256) void k_fuse(
    const float* __restrict__ temp, const float* __restrict__ Wtmp,
    const float* __restrict__ btmp, const float* __restrict__ Wg,
    const float* __restrict__ bg, const float* __restrict__ xph,
    const float* __restrict__ th, const float* __restrict__ uu,
    const float* __restrict__ dd, const float* __restrict__ pos,
    const __half* __restrict__ XG_h, float* __restrict__ out)
{
    const int ss = blockIdx.x >> 4;
    const int tt0 = (blockIdx.x & 15) * 4;
    const int tid = threadIdx.x;
    const int w = tid >> 6, lane = tid & 63;

    __shared__ float th_s[4][64], u_s[4][64], d_s[4][16];
    __shared__ float es[4][32], et[4][64], w10[4][10];
    __shared__ float gs[4][64];
    __shared__ float4 zz4[4][64];
    __shared__ float4 part4[4][4][64];    // temporal-xc partials [src wave][row][f4]
    __shared__ float4 part4b[4][4][64];   // WgP partials        [src wave][row][f4]

    {   // per-row vectors: wave w serves row tt0+w
        const size_t r = (size_t)(tt0 + w) * 32 + ss;
        th_s[w][lane] = th[r * 64 + lane];
        u_s[w][lane]  = uu[r * 64 + lane];
        if (lane < 16) d_s[w][lane] = dd[r * 16 + lane];
    }
    __syncthreads();   // A

    // ---- temporal scores (wave w -> row tt0+w, lane = t) ----
    {
        const int t = lane;
        const float4* xp = (const float4*)(xph + ((size_t)t * 32 + ss) * 64);
        const float4* tv4 = (const float4*)th_s[w];
        float sc = 0.f;
#pragma unroll
        for (int a = 0; a < 16; ++a) sc += dot4(xp[a], tv4[a]);
        const float2* tp = (const float2*)(temp + (((size_t)(tt0 + w) * 64 + t) * 32 + ss) * 10);
        const float2* dv = (const float2*)d_s[w];
        float2 tmpv[5];
#pragma unroll
        for (int q = 0; q < 5; ++q) {
            tmpv[q] = tp[q];
            const float2 d2 = dv[q];
            sc += tmpv[q].x * d2.x + tmpv[q].y * d2.y;
        }
        float m = sc;
#pragma unroll
        for (int off = 32; off; off >>= 1) m = fmaxf(m, __shfl_xor(m, off));
        const float e = __expf(sc - m);
        float s = e;
#pragma unroll
        for (int off = 32; off; off >>= 1) s += __shfl_xor(s, off);
        const float at = e / s;
        et[w][t] = at;
        float r10[10];
#pragma unroll
        for (int q = 0; q < 5; ++q) { r10[2 * q] = at * tmpv[q].x; r10[2 * q + 1] = at * tmpv[q].y; }
#pragma unroll
        for (int off = 32; off; off >>= 1) {
#pragma unroll
            for (int i = 0; i < 10; ++i) r10[i] += __shfl_xor(r10[i], off);
        }
        if (lane == 0) {
#pragma unroll
            for (int i = 0; i < 10; ++i) w10[w][i] = r10[i];
        }
    }

    // ---- spatial scores (waves 0-1: thread = ttl*32 + k) ----
    if (tid < 128) {
        const int ttl = tid >> 5, k = tid & 31;
        const float4* xp = (const float4*)(xph + ((size_t)(tt0 + ttl) * 32 + k) * 64);
        const float4* pp = (const float4*)(pos + ((size_t)ss * 32 + k) * 64);
        const float4* tv4 = (const float4*)th_s[ttl];
        const float4* uv4 = (const float4*)u_s[ttl];
        float sc = 0.f;
#pragma unroll
        for (int a = 0; a < 16; ++a) sc += dot4(xp[a], tv4[a]) + dot4(pp[a], uv4[a]);
        float m = sc;
#pragma unroll
        for (int off = 16; off; off >>= 1) m = fmaxf(m, __shfl_xor(m, off));
        const float e = __expf(sc - m);
        float s = e;
#pragma unroll
        for (int off = 16; off; off >>= 1) s += __shfl_xor(s, off);
        es[ttl][k] = e / s;
    }
    __syncthreads();   // B

    // ---- Phase C: gsum (wave w -> row w, lane = p) ----
    {
        const int p = lane;
        const float* pb = pos + (size_t)ss * 32 * 64 + p;
        float pv = 0.f;
#pragma unroll
        for (int k0 = 0; k0 < 32; k0 += 8) {
            float yv[8];
#pragma unroll
            for (int j = 0; j < 8; ++j) yv[j] = pb[(size_t)(k0 + j) * 64];
#pragma unroll
            for (int j = 0; j < 8; ++j) pv += es[w][k0 + j] * yv[j];
        }
        float g = pv + btmp[p];
#pragma unroll
        for (int q = 0; q < 10; ++q) g += w10[w][q] * Wtmp[q * 64 + p];
        gs[w][p] = g;
    }

    // ---- Phase C: temporal xc partials (wave w: t in [16w,16w+16)) ----
    {
        float4 acc[4];
#pragma unroll
        for (int r = 0; r < 4; ++r) acc[r] = make_float4(0.f, 0.f, 0.f, 0.f);
#pragma unroll
        for (int j = 0; j < 16; ++j) {
            const int t = 16 * w + j;
            const float4 x4 = ldh4(XG_h, ((size_t)t * 32 + ss) * 64 + lane);
#pragma unroll
            for (int r = 0; r < 4; ++r) acc[r] = f4fma(et[r][t], x4, acc[r]);
        }
#pragma unroll
        for (int r = 0; r < 4; ++r) part4[w][r][lane] = acc[r];
    }
    __syncthreads();   // C

    // ---- Phase D: spatial xc + temporal combine (wave w owns row w) ----
    {
        float4 a = make_float4(0.f, 0.f, 0.f, 0.f);
#pragma unroll
        for (int k = 0; k < 32; ++k) {
            const float4 x4 = ldh4(XG_h, ((size_t)(tt0 + w) * 32 + k) * 64 + lane);
            a = f4fma(es[w][k], x4, a);
        }
#pragma unroll
        for (int w2 = 0; w2 < 4; ++w2) a = f4add(a, part4[w2][w][lane]);
        zz4[w][lane] = a;
    }
    // ---- Phase D: WgP partials (wave w: p in [16w,16w+16), all 4 rows) ----
    {
        const float4* Wg4 = (const float4*)Wg;
        float4 acc[4];
#pragma unroll
        for (int r = 0; r < 4; ++r) acc[r] = make_float4(0.f, 0.f, 0.f, 0.f);
#pragma unroll
        for (int j = 0; j < 16; ++j) {
            const int pp = 16 * w + j;
            const float4 wg = Wg4[(size_t)(256 + pp) * 64 + lane];
#pragma unroll
            for (int r = 0; r < 4; ++r) acc[r] = f4fma(gs[r][pp], wg, acc[r]);
        }
#pragma unroll
        for (int r = 0; r < 4; ++r) part4b[w][r][lane] = acc[r];
    }
    __syncthreads();   // D

    // ---- Phase E: final reduce + store (wave w stores row tt0+w) ----
    {
        float4 o = f4add(zz4[w][lane], part4b[0][w][lane]);
        o = f4add(o, part4b[1][w][lane]);
        o = f4add(o, part4b[2][w][lane]);
        o = f4add(o, part4b[3][w][lane]);
        const float4 b4 = ((const float4*)bg)[lane];
        o.x += 2.f * b4.x; o.y += 2.f * b4.y; o.z += 2.f * b4.z; o.w += 2.f * b4.w;
        ((float4*)out)[((size_t)(tt0 + w) * 32 + ss) * 64 + lane] = o;
    }
}

extern "C" void kernel_launch(void* const* d_in, const int* in_sizes, int n_in,
                              void* d_out, int out_size, void* d_ws, size_t ws_size,
                              hipStream_t stream) {
    const float* bd   = (const float*)d_in[0];
    const float* positions = (const float*)d_in[1];
    const float* temp = (const float*)d_in[2];
    const float* Wa   = (const float*)d_in[3];
    const float* ba   = (const float*)d_in[4];
    const float* Wb   = (const float*)d_in[5];
    // d_in[6] = bb: constant shift inside both softmaxes; cancels
    const float* Wg   = (const float*)d_in[7];
    const float* bg   = (const float*)d_in[8];
    const float* Wpos = (const float*)d_in[9];
    const float* bpos = (const float*)d_in[10];
    const float* Wtmp = (const float*)d_in[11];
    const float* btmp = (const float*)d_in[12];
    float* out = (float*)d_out;

    float* ws  = (float*)d_ws;
    float* xph = ws + OFF_XPH;
    float* th  = ws + OFF_TH;
    float* uu  = ws + OFF_UU;
    float* dd  = ws + OFF_DD;
    float* pos = ws + OFF_POS;
    __half* XG_h = (__half*)(ws + OFF_XGH);

    k_pre<<<512, 256, 0, stream>>>(bd, Wa, ba, Wb, Wg, Wtmp, positions, Wpos,
                                   bpos, xph, th, uu, dd, pos, XG_h);
    k_fuse<<<512, 256, 0, stream>>>(temp, Wtmp, btmp, Wg, bg,
                                    xph, th, uu, dd, pos, XG_h, out);
}

// Round 8
// 110.688 us; speedup vs baseline: 1.9189x; 1.0030x over previous
//
#include <hip/hip_runtime.h>
#include <hip/hip_fp16.h>

constexpr int T = 64, S = 32, F = 256, A = 64;
constexpr int R = T * S;  // 2048

// workspace layout (fp32 element units)
constexpr size_t OFF_XPH = 0;                           // R*A
constexpr size_t OFF_TH  = OFF_XPH + (size_t)R * A;     // R*A
constexpr size_t OFF_UU  = OFF_TH  + (size_t)R * A;     // R*A
constexpr size_t OFF_DD  = OFF_UU  + (size_t)R * A;     // R*16
constexpr size_t OFF_POS = OFF_DD  + (size_t)R * 16;    // S*S*64
constexpr size_t OFF_XGH = OFF_POS + (size_t)S * S * 64;// R*F halfs = R*F/2 floats

constexpr int XLS = 68;   // xphL row stride (floats): 16B-aligned, low bank aliasing

__device__ __forceinline__ float dot4(float4 a, float4 b) {
    return a.x * b.x + a.y * b.y + a.z * b.z + a.w * b.w;
}
__device__ __forceinline__ float4 f4fma(float s, float4 v, float4 a) {
    a.x += s * v.x; a.y += s * v.y; a.z += s * v.z; a.w += s * v.w; return a;
}
__device__ __forceinline__ float4 f4add(float4 a, float4 b) {
    a.x += b.x; a.y += b.y; a.z += b.z; a.w += b.w; return a;
}
// load 4 halfs (8B coalesced) -> float4
__device__ __forceinline__ float4 ldh4(const __half* p, size_t idx4) {
    float2 raw = ((const float2*)p)[idx4];
    const __half2* h = reinterpret_cast<const __half2*>(&raw);
    const float2 lo = __half22float2(h[0]);
    const float2 hi = __half22float2(h[1]);
    return make_float4(lo.x, lo.y, hi.x, hi.y);
}

// ---------------------------------------------------------------------------
// K1: blocks 0..255: 8 x-rows each (2 rows per wave):
//   th = x@Wa + ba, xph = x@WbX, uu = WbP@th, dd = Wtmp@uu
// blocks 256..511: pos projection + XG = x@WgX for 8 rows, stored fp16.
// ---------------------------------------------------------------------------
__global__ __launch_bounds__(256) void k_pre(
    const float* __restrict__ bd, const float* __restrict__ Wa,
    const float* __restrict__ ba, const float* __restrict__ Wb,
    const float* __restrict__ Wg, const float* __restrict__ Wtmp,
    const float* __restrict__ positions, const float* __restrict__ Wpos,
    const float* __restrict__ bpos,
    float* __restrict__ xph, float* __restrict__ th,
    float* __restrict__ uu, float* __restrict__ dd,
    float* __restrict__ pos, __half* __restrict__ XG_h)
{
    const int blk = blockIdx.x;
    const int tid = threadIdx.x;

    __shared__ float xs[8 * 256];
    __shared__ float ths[8][64];
    __shared__ float us[8][64];

    if (blk >= 256) {  // ---- pos + XG blocks ----
        const int xb = blk - 256;
        {   // pos: idx covers S*S*64 exactly over 256 blocks
            const int idx = xb * 256 + tid;       // (j*32+k)*64 + p
            const int p = idx & 63, jk = idx >> 6;
            const int e = p >> 5, pp = p & 31;
            const float* src = positions + (size_t)(e * 1024 + jk) * 9;
            float acc = bpos[pp];
#pragma unroll
            for (int q = 0; q < 9; ++q) acc += src[q] * Wpos[q * 32 + pp];
            pos[idx] = acc;
        }
        {   // stage 8 x-rows
            const float4* src = (const float4*)(bd + (size_t)xb * 8 * 256);
            float4* dst = (float4*)xs;
            dst[tid] = src[tid];
            dst[tid + 256] = src[tid + 256];
        }
        __syncthreads();
        // XG[r][f] = sum_c x[r][c] * WgX[c][f];  f = tid (coalesced Wg)
        float acc[8] = {0.f, 0.f, 0.f, 0.f, 0.f, 0.f, 0.f, 0.f};
#pragma unroll
        for (int c0 = 0; c0 < 256; c0 += 8) {
            float wv[8];
#pragma unroll
            for (int j = 0; j < 8; ++j) wv[j] = Wg[(size_t)(c0 + j) * 256 + tid];
#pragma unroll
            for (int j = 0; j < 8; ++j) {
#pragma unroll
                for (int r = 0; r < 8; ++r) acc[r] += xs[r * 256 + c0 + j] * wv[j];
            }
        }
#pragma unroll
        for (int r = 0; r < 8; ++r)
            XG_h[(size_t)(xb * 8 + r) * 256 + tid] = __float2half(acc[r]);
        return;
    }

    // ---- row blocks ----
    const int w = tid >> 6, lane = tid & 63;
    const int row0 = blk * 8 + 2 * w;          // this wave's two rows

    {   // stage 8 rows of x
        const float4* src = (const float4*)(bd + (size_t)blk * 8 * 256);
        float4* dst = (float4*)xs;
        dst[tid] = src[tid];
        dst[tid + 256] = src[tid + 256];
    }
    __syncthreads();

    const float* x0 = xs + (2 * w) * 256;
    const float* x1 = xs + (2 * w + 1) * 256;
    float accA0 = ba[lane], accA1 = accA0, accB0 = 0.f, accB1 = 0.f;
#pragma unroll
    for (int c0 = 0; c0 < 256; c0 += 8) {
        float wa[8], wb[8];
#pragma unroll
        for (int j = 0; j < 8; ++j) wa[j] = Wa[(c0 + j) * 64 + lane];
#pragma unroll
        for (int j = 0; j < 8; ++j) wb[j] = Wb[(c0 + j) * 64 + lane];
#pragma unroll
        for (int j = 0; j < 8; ++j) {
            const float xa = x0[c0 + j], xb2 = x1[c0 + j];
            accA0 += xa * wa[j]; accA1 += xb2 * wa[j];
            accB0 += xa * wb[j]; accB1 += xb2 * wb[j];
        }
    }
    th[(size_t)row0 * 64 + lane] = accA0;
    th[(size_t)(row0 + 1) * 64 + lane] = accA1;
    xph[(size_t)row0 * 64 + lane] = accB0;
    xph[(size_t)(row0 + 1) * 64 + lane] = accB1;
    ths[2 * w][lane] = accA0; ths[2 * w + 1][lane] = accA1;
    __syncthreads();

    float accU0 = 0.f, accU1 = 0.f;
#pragma unroll 8
    for (int a = 0; a < 64; ++a) {
        const float wp = Wb[(256 + lane) * 64 + a];
        accU0 += ths[2 * w][a] * wp;
        accU1 += ths[2 * w + 1][a] * wp;
    }
    uu[(size_t)row0 * 64 + lane] = accU0;
    uu[(size_t)(row0 + 1) * 64 + lane] = accU1;
    us[2 * w][lane] = accU0; us[2 * w + 1][lane] = accU1;
    __syncthreads();

    const int rsel = lane >> 4, q = lane & 15;
    if (rsel < 2 && q < 10) {
        float accD = 0.f;
#pragma unroll 8
        for (int p2 = 0; p2 < 64; ++p2) accD += us[2 * w + rsel][p2] * Wtmp[q * 64 + p2];
        dd[(size_t)(row0 + rsel) * 16 + q] = accD;
    }
}

// ---------------------------------------------------------------------------
// K2 (fused): one block per (ss, 4 consecutive tt).  blockIdx = ss*16 + tt0/4
// (keeps blk%8 = tt0-group%8: same-tt0 blocks -> same XCD, pinning the 32 KB
// of shared spatial key rows in one XCD's L2).
//   A: stage 64 temporal key rows xph[t*32+ss] into LDS (coalesced, shared
//      by all 4 waves); temporal scores+softmax+w10; spatial scores.
//   C: gsum; temporal xc partials over fp16 XG (t split by wave)
//   D: spatial xc + combine -> zz4; WgP partials (p split by wave)
//   E: final cross-wave reduce + 2bg + float4 store
// ---------------------------------------------------------------------------
__global__ __launch_bounds__(256) void k_fuse(
    const float* __restrict__ temp, const float* __restrict__ Wtmp,
    const float* __restrict__ btmp, const float* __restrict__ Wg,
    const float* __restrict__ bg, const float* __restrict__ xph,
    const float* __restrict__ th, const float* __restrict__ uu,
    const float* __restrict__ dd, const float* __restrict__ pos,
    const __half* __restrict__ XG_h, float* __restrict__ out)
{
    const int ss = blockIdx.x >> 4;
    const int tt0 = (blockIdx.x & 15) * 4;
    const int tid = threadIdx.x;
    const int w = tid >> 6, lane = tid & 63;

    __shared__ float th_s[4][64], u_s[4][64], d_s[4][16];
    __shared__ float es[4][32], et[4][64], w10[4][10];
    __shared__ float gs[4][64];
    __shared__ float xphL[64 * XLS];      // temporal key rows, LDS-staged
    __shared__ float4 zz4[4][64];
    __shared__ float4 part4[4][4][64];    // temporal-xc partials [src wave][row][f4]
    __shared__ float4 part4b[4][4][64];   // WgP partials        [src wave][row][f4]

    {   // per-row vectors: wave w serves row tt0+w
        const size_t r = (size_t)(tt0 + w) * 32 + ss;
        th_s[w][lane] = th[r * 64 + lane];
        u_s[w][lane]  = uu[r * 64 + lane];
        if (lane < 16) d_s[w][lane] = dd[r * 16 + lane];
    }
    // stage temporal keys: 64 rows x 64 floats, coalesced 256B wave-insts
    for (int i = tid; i < 64 * 64; i += 256) {
        const int row = i >> 6, a = i & 63;
        xphL[row * XLS + a] = xph[((size_t)row * 32 + ss) * 64 + a];
    }
    __syncthreads();   // A

    // ---- temporal scores (wave w -> row tt0+w, lane = t) ----
    {
        const int t = lane;
        const float4* xp = (const float4*)&xphL[t * XLS];
        const float4* tv4 = (const float4*)th_s[w];
        float sc = 0.f;
#pragma unroll
        for (int a = 0; a < 16; ++a) sc += dot4(xp[a], tv4[a]);
        const float2* tp = (const float2*)(temp + (((size_t)(tt0 + w) * 64 + t) * 32 + ss) * 10);
        const float2* dv = (const float2*)d_s[w];
        float2 tmpv[5];
#pragma unroll
        for (int q = 0; q < 5; ++q) {
            tmpv[q] = tp[q];
            const float2 d2 = dv[q];
            sc += tmpv[q].x * d2.x + tmpv[q].y * d2.y;
        }
        float m = sc;
#pragma unroll
        for (int off = 32; off; off >>= 1) m = fmaxf(m, __shfl_xor(m, off));
        const float e = __expf(sc - m);
        float s = e;
#pragma unroll
        for (int off = 32; off; off >>= 1) s += __shfl_xor(s, off);
        const float at = e / s;
        et[w][t] = at;
        float r10[10];
#pragma unroll
        for (int q = 0; q < 5; ++q) { r10[2 * q] = at * tmpv[q].x; r10[2 * q + 1] = at * tmpv[q].y; }
#pragma unroll
        for (int off = 32; off; off >>= 1) {
#pragma unroll
            for (int i = 0; i < 10; ++i) r10[i] += __shfl_xor(r10[i], off);
        }
        if (lane == 0) {
#pragma unroll
            for (int i = 0; i < 10; ++i) w10[w][i] = r10[i];
        }
    }

    // ---- spatial scores (waves 0-1: thread = ttl*32 + k) ----
    if (tid < 128) {
        const int ttl = tid >> 5, k = tid & 31;
        const float4* xp = (const float4*)(xph + ((size_t)(tt0 + ttl) * 32 + k) * 64);
        const float4* pp = (const float4*)(pos + ((size_t)ss * 32 + k) * 64);
        const float4* tv4 = (const float4*)th_s[ttl];
        const float4* uv4 = (const float4*)u_s[ttl];
        float sc = 0.f;
#pragma unroll
        for (int a = 0; a < 16; ++a) sc += dot4(xp[a], tv4[a]) + dot4(pp[a], uv4[a]);
        float m = sc;
#pragma unroll
        for (int off = 16; off; off >>= 1) m = fmaxf(m, __shfl_xor(m, off));
        const float e = __expf(sc - m);
        float s = e;
#pragma unroll
        for (int off = 16; off; off >>= 1) s += __shfl_xor(s, off);
        es[ttl][k] = e / s;
    }
    __syncthreads();   // B

    // ---- Phase C: gsum (wave w -> row w, lane = p) ----
    {
        const int p = lane;
        const float* pb = pos + (size_t)ss * 32 * 64 + p;
        float pv = 0.f;
#pragma unroll
        for (int k0 = 0; k0 < 32; k0 += 8) {
            float yv[8];
#pragma unroll
            for (int j = 0; j < 8; ++j) yv[j] = pb[(size_t)(k0 + j) * 64];
#pragma unroll
            for (int j = 0; j < 8; ++j) pv += es[w][k0 + j] * yv[j];
        }
        float g = pv + btmp[p];
#pragma unroll
        for (int q = 0; q < 10; ++q) g += w10[w][q] * Wtmp[q * 64 + p];
        gs[w][p] = g;
    }

    // ---- Phase C: temporal xc partials (wave w: t in [16w,16w+16)) ----
    {
        float4 acc[4];
#pragma unroll
        for (int r = 0; r < 4; ++r) acc[r] = make_float4(0.f, 0.f, 0.f, 0.f);
#pragma unroll
        for (int j = 0; j < 16; ++j) {
            const int t = 16 * w + j;
            const float4 x4 = ldh4(XG_h, ((size_t)t * 32 + ss) * 64 + lane);
#pragma unroll
            for (int r = 0; r < 4; ++r) acc[r] = f4fma(et[r][t], x4, acc[r]);
        }
#pragma unroll
        for (int r = 0; r < 4; ++r) part4[w][r][lane] = acc[r];
    }
    __syncthreads();   // C

    // ---- Phase D: spatial xc + temporal combine (wave w owns row w) ----
    {
        float4 a = make_float4(0.f, 0.f, 0.f, 0.f);
#pragma unroll
        for (int k = 0; k < 32; ++k) {
            const float4 x4 = ldh4(XG_h, ((size_t)(tt0 + w) * 32 + k) * 64 + lane);
            a = f4fma(es[w][k], x4, a);
        }
#pragma unroll
        for (int w2 = 0; w2 < 4; ++w2) a = f4add(a, part4[w2][w][lane]);
        zz4[w][lane] = a;
    }
    // ---- Phase D: WgP partials (wave w: p in [16w,16w+16), all 4 rows) ----
    {
        const float4* Wg4 = (const float4*)Wg;
        float4 acc[4];
#pragma unroll
        for (int r = 0; r < 4; ++r) acc[r] = make_float4(0.f, 0.f, 0.f, 0.f);
#pragma unroll
        for (int j = 0; j < 16; ++j) {
            const int pp = 16 * w + j;
            const float4 wg = Wg4[(size_t)(256 + pp) * 64 + lane];
#pragma unroll
            for (int r = 0; r < 4; ++r) acc[r] = f4fma(gs[r][pp], wg, acc[r]);
        }
#pragma unroll
        for (int r = 0; r < 4; ++r) part4b[w][r][lane] = acc[r];
    }
    __syncthreads();   // D

    // ---- Phase E: final reduce + store (wave w stores row tt0+w) ----
    {
        float4 o = f4add(zz4[w][lane], part4b[0][w][lane]);
        o = f4add(o, part4b[1][w][lane]);
        o = f4add(o, part4b[2][w][lane]);
        o = f4add(o, part4b[3][w][lane]);
        const float4 b4 = ((const float4*)bg)[lane];
        o.x += 2.f * b4.x; o.y += 2.f * b4.y; o.z += 2.f * b4.z; o.w += 2.f * b4.w;
        ((float4*)out)[((size_t)(tt0 + w) * 32 + ss) * 64 + lane] = o;
    }
}

extern "C" void kernel_launch(void* const* d_in, const int* in_sizes, int n_in,
                              void* d_out, int out_size, void* d_ws, size_t ws_size,
                              hipStream_t stream) {
    const float* bd   = (const float*)d_in[0];
    const float* positions = (const float*)d_in[1];
    const float* temp = (const float*)d_in[2];
    const float* Wa   = (const float*)d_in[3];
    const float* ba   = (const float*)d_in[4];
    const float* Wb   = (const float*)d_in[5];
    // d_in[6] = bb: constant shift inside both softmaxes; cancels
    const float* Wg   = (const float*)d_in[7];
    const float* bg   = (const float*)d_in[8];
    const float* Wpos = (const float*)d_in[9];
    const float* bpos = (const float*)d_in[10];
    const float* Wtmp = (const float*)d_in[11];
    const float* btmp = (const float*)d_in[12];
    float* out = (float*)d_out;

    float* ws  = (float*)d_ws;
    float* xph = ws + OFF_XPH;
    float* th  = ws + OFF_TH;
    float* uu  = ws + OFF_UU;
    float* dd  = ws + OFF_DD;
    float* pos = ws + OFF_POS;
    __half* XG_h = (__half*)(ws + OFF_XGH);

    k_pre<<<512, 256, 0, stream>>>(bd, Wa, ba, Wb, Wg, Wtmp, positions, Wpos,
                                   bpos, xph, th, uu, dd, pos, XG_h);
    k_fuse<<<512, 256, 0, stream>>>(temp, Wtmp, btmp, Wg, bg,
                                    xph, th, uu, dd, pos, XG_h, out);
}